// Round 1
// baseline (637.441 us; speedup 1.0000x reference)
//
#include <hip/hip_runtime.h>
#include <hip/hip_bf16.h>
#include <math.h>

constexpr int B_ = 2;
constexpr int N_ = 1024;
constexpr int D_ = 256;
constexpr int H_ = 8;
constexpr int DH_ = 32;
constexpr float SCALE_ = 0.17677669529663687f;  // 1/sqrt(32)
constexpr float EPSV_ = 1e-4f;

// ---------------------------------------------------------------------------
// Projection GEMM: out[r][o] = sum_k in[r][k] * W[o][k]   (M=2048, K=N=256)
// mode 0: headed layout out[((b*H + o/DH)*N_ + n)*DH + o%DH], r = b*N_+n
// mode 1: flat layout   out[r*D_ + o]
// Block: 256 threads, 32-row tile, each thread owns one output column.
// ---------------------------------------------------------------------------
__global__ __launch_bounds__(256)
void proj_kernel(const float* __restrict__ in, const float* __restrict__ W,
                 float* __restrict__ out, int mode) {
  __shared__ float s_lds[32][36];   // [kk][r], pad 36 keeps b128 alignment
  __shared__ float w_lds[256][33];  // [o][kk]
  const int tid = threadIdx.x;
  const int r0 = blockIdx.x * 32;
  float acc[32];
#pragma unroll
  for (int r = 0; r < 32; ++r) acc[r] = 0.f;

  for (int k0 = 0; k0 < D_; k0 += 32) {
    __syncthreads();
#pragma unroll
    for (int it = 0; it < 4; ++it) {
      int idx = tid + it * 256;
      int r = idx >> 5, kk = idx & 31;
      s_lds[kk][r] = in[(r0 + r) * D_ + k0 + kk];  // transposed store
    }
#pragma unroll
    for (int it = 0; it < 32; ++it) {
      int idx = tid + it * 256;
      int o = idx >> 5, kk = idx & 31;
      w_lds[o][kk] = W[o * D_ + k0 + kk];
    }
    __syncthreads();
    float wreg[32];
#pragma unroll
    for (int kk = 0; kk < 32; ++kk) wreg[kk] = w_lds[tid][kk];
#pragma unroll
    for (int kk = 0; kk < 32; ++kk) {
#pragma unroll
      for (int r = 0; r < 32; ++r) acc[r] += s_lds[kk][r] * wreg[kk];
    }
  }

  const int o = tid;
  if (mode == 0) {
    int h = o >> 5, d = o & 31;
#pragma unroll
    for (int r = 0; r < 32; ++r) {
      int rr = r0 + r;
      int b = rr >> 10, n = rr & 1023;
      out[((b * H_ + h) * N_ + n) * DH_ + d] = acc[r];
    }
  } else {
#pragma unroll
    for (int r = 0; r < 32; ++r) out[(r0 + r) * D_ + o] = acc[r];
  }
}

// ---------------------------------------------------------------------------
// Pair-bias kernel: bias[b][i][j] = geomMLP(dist,dt) + gamma log-prob term.
// Each thread owns one j and 4 consecutive i's. The xyz_j part of the
// delay-MLP hidden layer is j-only -> precomputed once per thread (dpre[64]).
// ---------------------------------------------------------------------------
__global__ __launch_bounds__(256)
void bias_kernel(const float* __restrict__ coords,
                 const float* __restrict__ gw1, const float* __restrict__ gb1,
                 const float* __restrict__ gw2, const float* __restrict__ gb2,
                 const float* __restrict__ dw1, const float* __restrict__ db1,
                 const float* __restrict__ dw2, const float* __restrict__ db2,
                 float* __restrict__ bias) {
  __shared__ float sw[704];
  const int tid = threadIdx.x;
  if (tid < 64) {
    int h = tid;
    sw[h]       = gw1[2 * h];
    sw[64 + h]  = gw1[2 * h + 1];
    sw[128 + h] = gb1[h];
    sw[192 + h] = gw2[h];
    sw[256 + h] = dw1[4 * h];
    sw[320 + h] = dw1[4 * h + 1];
    sw[384 + h] = dw1[4 * h + 2];
    sw[448 + h] = dw1[4 * h + 3];
    sw[512 + h] = db1[h];
    sw[576 + h] = dw2[h];
    sw[640 + h] = dw2[64 + h];
  }
  __syncthreads();

  const int bi = blockIdx.x;
  const int jt = bi & 3;           // 4 j-tiles of 256
  const int it = (bi >> 2) & 255;  // 256 i-tiles of 4
  const int b  = bi >> 10;
  const int j  = jt * 256 + tid;
  const int ibase = it * 4;

  const float4 cj = ((const float4*)coords)[b * N_ + j];
  float dist[4], dtv[4];
#pragma unroll
  for (int ii = 0; ii < 4; ++ii) {
    float4 ci = ((const float4*)coords)[b * N_ + ibase + ii];
    float dx = ci.x - cj.x, dy = ci.y - cj.y, dz = ci.z - cj.z;
    dist[ii] = sqrtf(dx * dx + dy * dy + dz * dz);
    dtv[ii]  = ci.w - cj.w;
  }

  // j-only part of delay-MLP hidden pre-activation
  float dpre[64];
#pragma unroll
  for (int h = 0; h < 64; ++h)
    dpre[h] = fmaf(sw[320 + h], cj.x,
              fmaf(sw[384 + h], cj.y,
              fmaf(sw[448 + h], cj.z, sw[512 + h])));

  const float db20 = db2[0], db21 = db2[1], gb20 = gb2[0];
  float biasv[4], raw0[4], raw1[4];
#pragma unroll
  for (int ii = 0; ii < 4; ++ii) { biasv[ii] = 0.f; raw0[ii] = db20; raw1[ii] = db21; }

#pragma unroll
  for (int h = 0; h < 64; ++h) {
    float g0 = sw[h], g1 = sw[64 + h], gb = sw[128 + h], g2 = sw[192 + h];
    float d0 = sw[256 + h], w0 = sw[576 + h], w1 = sw[640 + h];
    float dp = dpre[h];
#pragma unroll
    for (int ii = 0; ii < 4; ++ii) {
      float g = fmaf(g0, dist[ii], fmaf(g1, dtv[ii], gb));
      biasv[ii] = fmaf(g2, fmaxf(g, 0.f), biasv[ii]);
      float dh_ = fmaxf(fmaf(d0, dist[ii], dp), 0.f);
      raw0[ii] = fmaf(w0, dh_, raw0[ii]);
      raw1[ii] = fmaf(w1, dh_, raw1[ii]);
    }
  }

#pragma unroll
  for (int ii = 0; ii < 4; ++ii) {
    float sh  = log1pf(expf(raw0[ii])) + EPSV_;   // softplus + eps
    float ra  = log1pf(expf(raw1[ii])) + EPSV_;
    float dtp = fmaxf(fabsf(dtv[ii]), EPSV_);
    float lp  = sh * logf(ra) + (sh - 1.f) * logf(dtp) - ra * dtp - lgammaf(sh);
    bias[(b * N_ + ibase + ii) * N_ + j] = biasv[ii] + gb20 + lp;
  }
}

// ---------------------------------------------------------------------------
// Fused flash attention: one wave per query row, 4 waves/block share k/v tiles.
// outpre[b][n][h*DH+d] = softmax_j(scale*q.k + bias[b][n][j]) @ v
// ---------------------------------------------------------------------------
__global__ __launch_bounds__(256)
void attn_kernel(const float* __restrict__ qg, const float* __restrict__ kg,
                 const float* __restrict__ vg, const float* __restrict__ biasg,
                 float* __restrict__ outpre) {
  constexpr int JT = 64;
  __shared__ float k_lds[JT][33];       // [jj][d]
  __shared__ float vT_lds[DH_][JT + 1]; // [d][jj]
  __shared__ float p_lds[4][64];

  const int tid  = threadIdx.x;
  const int w    = tid >> 6;
  const int lane = tid & 63;
  const int i0   = (blockIdx.x & (N_ / 4 - 1)) * 4;
  const int bh   = blockIdx.x >> 8;
  const int b    = bh >> 3, h = bh & 7;

  const float* kbase = kg + bh * N_ * DH_;
  const float* vbase = vg + bh * N_ * DH_;
  const float* qrow  = qg + (bh * N_ + i0 + w) * DH_;
  const float* brow  = biasg + (b * N_ + i0 + w) * N_;

  float qreg[DH_];
#pragma unroll
  for (int d = 0; d < DH_; ++d) qreg[d] = qrow[d];

  float m_run = -1e30f, l_run = 0.f, acc = 0.f;
  const int d  = lane & 31;
  const int hf = lane >> 5;

  for (int j0 = 0; j0 < N_; j0 += JT) {
    __syncthreads();
#pragma unroll
    for (int itl = 0; itl < 8; ++itl) {
      int idx = tid + itl * 256;
      int jj = idx >> 5, dd = idx & 31;
      float kvv = kbase[(j0 + jj) * DH_ + dd];
      float vvv = vbase[(j0 + jj) * DH_ + dd];
      k_lds[jj][dd]  = kvv;
      vT_lds[dd][jj] = vvv;
    }
    __syncthreads();

    // score for j = j0 + lane
    float s = 0.f;
#pragma unroll
    for (int dd = 0; dd < DH_; ++dd) s += qreg[dd] * k_lds[lane][dd];
    s = s * SCALE_ + brow[j0 + lane];

    // wave-wide online softmax
    float m_tile = s;
#pragma unroll
    for (int off = 32; off >= 1; off >>= 1)
      m_tile = fmaxf(m_tile, __shfl_xor(m_tile, off));
    float m_new = fmaxf(m_run, m_tile);
    float p    = __expf(s - m_new);
    float corr = __expf(m_run - m_new);
    float psum = p;
#pragma unroll
    for (int off = 32; off >= 1; off >>= 1)
      psum += __shfl_xor(psum, off);
    l_run = l_run * corr + psum;
    m_run = m_new;
    acc *= corr;

    p_lds[w][lane] = p;
#pragma unroll
    for (int jj = 0; jj < 32; ++jj) {
      int jidx = hf * 32 + jj;
      acc = fmaf(p_lds[w][jidx], vT_lds[d][jidx], acc);
    }
  }

  float acc_o = __shfl_xor(acc, 32);
  if (hf == 0) {
    float o = (acc + acc_o) / l_run;
    outpre[((b * N_ + i0 + w) * H_ + h) * DH_ + d] = o;
  }
}

// ---------------------------------------------------------------------------
extern "C" void kernel_launch(void* const* d_in, const int* in_sizes, int n_in,
                              void* d_out, int out_size, void* d_ws, size_t ws_size,
                              hipStream_t stream) {
  const float* src    = (const float*)d_in[0];
  const float* coords = (const float*)d_in[1];
  const float* Wq  = (const float*)d_in[2];
  const float* Wk  = (const float*)d_in[3];
  const float* Wv  = (const float*)d_in[4];
  const float* Wo  = (const float*)d_in[5];
  const float* gw1 = (const float*)d_in[6];
  const float* gb1 = (const float*)d_in[7];
  const float* gw2 = (const float*)d_in[8];
  const float* gb2 = (const float*)d_in[9];
  const float* dw1 = (const float*)d_in[10];
  const float* db1 = (const float*)d_in[11];
  const float* dw2 = (const float*)d_in[12];
  const float* db2 = (const float*)d_in[13];
  float* out = (float*)d_out;

  float* ws = (float*)d_ws;
  float* qw     = ws;                 // 524288 floats
  float* kw     = ws + 524288;        // 524288
  float* vw     = ws + 1048576;       // 524288
  float* biasw  = ws + 1572864;       // 2097152
  float* outpre = ws + 3670016;       // 524288  (total 16 MB)

  proj_kernel<<<64, 256, 0, stream>>>(src, Wq, qw, 0);
  proj_kernel<<<64, 256, 0, stream>>>(src, Wk, kw, 0);
  proj_kernel<<<64, 256, 0, stream>>>(src, Wv, vw, 0);
  bias_kernel<<<2048, 256, 0, stream>>>(coords, gw1, gb1, gw2, gb2,
                                        dw1, db1, dw2, db2, biasw);
  attn_kernel<<<4096, 256, 0, stream>>>(qw, kw, vw, biasw, outpre);
  proj_kernel<<<64, 256, 0, stream>>>(outpre, Wo, out, 1);
}

// Round 2
// 268.466 us; speedup vs baseline: 2.3744x; 2.3744x over previous
//
#include <hip/hip_runtime.h>
#include <hip/hip_bf16.h>
#include <math.h>

constexpr int B_ = 2;
constexpr int N_ = 1024;
constexpr int D_ = 256;
constexpr int H_ = 8;
constexpr int DH_ = 32;
constexpr float SCALE_ = 0.17677669529663687f;  // 1/sqrt(32)
constexpr float EPSV_ = 1e-4f;

// ---------------------------------------------------------------------------
// Fast lgamma for x in (0, 2]:  A&S 6.1.36 poly for Gamma(1+y), |err|<=3e-7.
// lgamma(x) = log(Gamma(1+y)) - (x<1 ? log(x) : 0), y = x<1 ? x : x-1.
// ---------------------------------------------------------------------------
__device__ __forceinline__ float lgamma_fast(float x) {
  float y = (x < 1.f) ? x : (x - 1.f);
  float g = fmaf(y, 0.035868343f, -0.193527818f);
  g = fmaf(y, g, 0.482199394f);
  g = fmaf(y, g, -0.756704078f);
  g = fmaf(y, g, 0.918206857f);
  g = fmaf(y, g, -0.897056937f);
  g = fmaf(y, g, 0.988205891f);
  g = fmaf(y, g, -0.577191652f);
  g = fmaf(y, g, 1.0f);
  float lg = __logf(g);
  return (x < 1.f) ? lg - __logf(x) : lg;
}

__device__ __forceinline__ float softplus_fast(float x) {
  return __logf(1.f + __expf(x));
}

// ---------------------------------------------------------------------------
// Projection GEMM: out[r][o] = sum_k in[r][k] * W[o][k]   (M=2048, K=N=256)
// mode 0: headed layout out[((b*H + o/DH)*N_ + n)*DH + o%DH], r = b*N_+n
// mode 1: flat layout   out[r*D_ + o]
// ---------------------------------------------------------------------------
__device__ __forceinline__
void proj_body(const float* __restrict__ in, const float* __restrict__ W,
               float* __restrict__ out, int mode, int blk) {
  __shared__ float s_lds[32][36];
  __shared__ float w_lds[256][33];
  const int tid = threadIdx.x;
  const int r0 = blk * 32;
  float acc[32];
#pragma unroll
  for (int r = 0; r < 32; ++r) acc[r] = 0.f;

  for (int k0 = 0; k0 < D_; k0 += 32) {
    __syncthreads();
#pragma unroll
    for (int it = 0; it < 4; ++it) {
      int idx = tid + it * 256;
      int r = idx >> 5, kk = idx & 31;
      s_lds[kk][r] = in[(r0 + r) * D_ + k0 + kk];
    }
#pragma unroll
    for (int it = 0; it < 32; ++it) {
      int idx = tid + it * 256;
      int o = idx >> 5, kk = idx & 31;
      w_lds[o][kk] = W[o * D_ + k0 + kk];
    }
    __syncthreads();
    float wreg[32];
#pragma unroll
    for (int kk = 0; kk < 32; ++kk) wreg[kk] = w_lds[tid][kk];
#pragma unroll
    for (int kk = 0; kk < 32; ++kk) {
#pragma unroll
      for (int r = 0; r < 32; ++r) acc[r] += s_lds[kk][r] * wreg[kk];
    }
  }

  const int o = tid;
  if (mode == 0) {
    int h = o >> 5, d = o & 31;
#pragma unroll
    for (int r = 0; r < 32; ++r) {
      int rr = r0 + r;
      int b = rr >> 10, n = rr & 1023;
      out[((b * H_ + h) * N_ + n) * DH_ + d] = acc[r];
    }
  } else {
#pragma unroll
    for (int r = 0; r < 32; ++r) out[(r0 + r) * D_ + o] = acc[r];
  }
}

__global__ __launch_bounds__(256)
void qkv_kernel(const float* __restrict__ src,
                const float* __restrict__ Wq, const float* __restrict__ Wk,
                const float* __restrict__ Wv,
                float* __restrict__ qw, float* __restrict__ kw,
                float* __restrict__ vw) {
  const float* W = (blockIdx.y == 0) ? Wq : (blockIdx.y == 1) ? Wk : Wv;
  float* out     = (blockIdx.y == 0) ? qw : (blockIdx.y == 1) ? kw : vw;
  proj_body(src, W, out, 0, blockIdx.x);
}

__global__ __launch_bounds__(256)
void proj_kernel(const float* __restrict__ in, const float* __restrict__ W,
                 float* __restrict__ out, int mode) {
  proj_body(in, W, out, mode, blockIdx.x);
}

// ---------------------------------------------------------------------------
// Pair-bias kernel. Each thread: one j, 4 consecutive i's. Weights packed as
// float4 LDS broadcasts; j-only delay pre-activation recomputed in-loop
// (3 FMA per h, amortized over 4 pairs) to keep VGPR count low (no spills).
// ---------------------------------------------------------------------------
__global__ __launch_bounds__(256)
void bias_kernel(const float* __restrict__ coords,
                 const float* __restrict__ gw1, const float* __restrict__ gb1,
                 const float* __restrict__ gw2, const float* __restrict__ gb2,
                 const float* __restrict__ dw1, const float* __restrict__ db1,
                 const float* __restrict__ dw2, const float* __restrict__ db2,
                 float* __restrict__ bias) {
  __shared__ float4 swA[64];  // g0, g1, gb1, g2
  __shared__ float4 swB[64];  // d_dist, d_x, d_y, d_z
  __shared__ float4 swC[64];  // db1, w0, w1, pad
  const int tid = threadIdx.x;
  if (tid < 64) {
    int h = tid;
    swA[h] = make_float4(gw1[2 * h], gw1[2 * h + 1], gb1[h], gw2[h]);
    swB[h] = make_float4(dw1[4 * h], dw1[4 * h + 1], dw1[4 * h + 2], dw1[4 * h + 3]);
    swC[h] = make_float4(db1[h], dw2[h], dw2[64 + h], 0.f);
  }
  __syncthreads();

  const int bi = blockIdx.x;
  const int jt = bi & 3;
  const int it = (bi >> 2) & 255;
  const int b  = bi >> 10;
  const int j  = jt * 256 + tid;
  const int ibase = it * 4;

  const float4 cj = ((const float4*)coords)[b * N_ + j];
  float dist[4], dtv[4];
#pragma unroll
  for (int ii = 0; ii < 4; ++ii) {
    float4 ci = ((const float4*)coords)[b * N_ + ibase + ii];
    float dx = ci.x - cj.x, dy = ci.y - cj.y, dz = ci.z - cj.z;
    dist[ii] = sqrtf(dx * dx + dy * dy + dz * dz);
    dtv[ii]  = ci.w - cj.w;
  }

  const float db20 = db2[0], db21 = db2[1], gb20 = gb2[0];
  float biasv[4], raw0[4], raw1[4];
#pragma unroll
  for (int ii = 0; ii < 4; ++ii) { biasv[ii] = 0.f; raw0[ii] = db20; raw1[ii] = db21; }

#pragma unroll 8
  for (int h = 0; h < 64; ++h) {
    float4 a = swA[h], w = swB[h], c = swC[h];
    float dp = fmaf(w.y, cj.x, fmaf(w.z, cj.y, fmaf(w.w, cj.z, c.x)));
#pragma unroll
    for (int ii = 0; ii < 4; ++ii) {
      float g = fmaf(a.x, dist[ii], fmaf(a.y, dtv[ii], a.z));
      biasv[ii] = fmaf(a.w, fmaxf(g, 0.f), biasv[ii]);
      float dh_ = fmaxf(fmaf(w.x, dist[ii], dp), 0.f);
      raw0[ii] = fmaf(c.y, dh_, raw0[ii]);
      raw1[ii] = fmaf(c.z, dh_, raw1[ii]);
    }
  }

#pragma unroll
  for (int ii = 0; ii < 4; ++ii) {
    float sh  = softplus_fast(raw0[ii]) + EPSV_;
    float ra  = softplus_fast(raw1[ii]) + EPSV_;
    float dtp = fmaxf(fabsf(dtv[ii]), EPSV_);
    float lp  = sh * __logf(ra) + (sh - 1.f) * __logf(dtp) - ra * dtp - lgamma_fast(sh);
    bias[(b * N_ + ibase + ii) * N_ + j] = biasv[ii] + gb20 + lp;
  }
}

// ---------------------------------------------------------------------------
// Fused flash attention: one wave per query row, 4 waves/block share k/v tiles.
// ---------------------------------------------------------------------------
__global__ __launch_bounds__(256)
void attn_kernel(const float* __restrict__ qg, const float* __restrict__ kg,
                 const float* __restrict__ vg, const float* __restrict__ biasg,
                 float* __restrict__ outpre) {
  constexpr int JT = 64;
  __shared__ float k_lds[JT][33];
  __shared__ float vT_lds[DH_][JT + 1];
  __shared__ float p_lds[4][64];

  const int tid  = threadIdx.x;
  const int w    = tid >> 6;
  const int lane = tid & 63;
  const int i0   = (blockIdx.x & (N_ / 4 - 1)) * 4;
  const int bh   = blockIdx.x >> 8;
  const int b    = bh >> 3, h = bh & 7;

  const float* kbase = kg + bh * N_ * DH_;
  const float* vbase = vg + bh * N_ * DH_;
  const float* qrow  = qg + (bh * N_ + i0 + w) * DH_;
  const float* brow  = biasg + (b * N_ + i0 + w) * N_;

  float qreg[DH_];
#pragma unroll
  for (int d = 0; d < DH_; ++d) qreg[d] = qrow[d];

  float m_run = -1e30f, l_run = 0.f, acc = 0.f;
  const int d  = lane & 31;
  const int hf = lane >> 5;

  for (int j0 = 0; j0 < N_; j0 += JT) {
    __syncthreads();
#pragma unroll
    for (int itl = 0; itl < 8; ++itl) {
      int idx = tid + itl * 256;
      int jj = idx >> 5, dd = idx & 31;
      float kvv = kbase[(j0 + jj) * DH_ + dd];
      float vvv = vbase[(j0 + jj) * DH_ + dd];
      k_lds[jj][dd]  = kvv;
      vT_lds[dd][jj] = vvv;
    }
    __syncthreads();

    float s = 0.f;
#pragma unroll
    for (int dd = 0; dd < DH_; ++dd) s += qreg[dd] * k_lds[lane][dd];
    s = s * SCALE_ + brow[j0 + lane];

    float m_tile = s;
#pragma unroll
    for (int off = 32; off >= 1; off >>= 1)
      m_tile = fmaxf(m_tile, __shfl_xor(m_tile, off));
    float m_new = fmaxf(m_run, m_tile);
    float p    = __expf(s - m_new);
    float corr = __expf(m_run - m_new);
    float psum = p;
#pragma unroll
    for (int off = 32; off >= 1; off >>= 1)
      psum += __shfl_xor(psum, off);
    l_run = l_run * corr + psum;
    m_run = m_new;
    acc *= corr;

    p_lds[w][lane] = p;
#pragma unroll
    for (int jj = 0; jj < 32; ++jj) {
      int jidx = hf * 32 + jj;
      acc = fmaf(p_lds[w][jidx], vT_lds[d][jidx], acc);
    }
  }

  float acc_o = __shfl_xor(acc, 32);
  if (hf == 0) {
    float o = (acc + acc_o) / l_run;
    outpre[((b * N_ + i0 + w) * H_ + h) * DH_ + d] = o;
  }
}

// ---------------------------------------------------------------------------
extern "C" void kernel_launch(void* const* d_in, const int* in_sizes, int n_in,
                              void* d_out, int out_size, void* d_ws, size_t ws_size,
                              hipStream_t stream) {
  const float* src    = (const float*)d_in[0];
  const float* coords = (const float*)d_in[1];
  const float* Wq  = (const float*)d_in[2];
  const float* Wk  = (const float*)d_in[3];
  const float* Wv  = (const float*)d_in[4];
  const float* Wo  = (const float*)d_in[5];
  const float* gw1 = (const float*)d_in[6];
  const float* gb1 = (const float*)d_in[7];
  const float* gw2 = (const float*)d_in[8];
  const float* gb2 = (const float*)d_in[9];
  const float* dw1 = (const float*)d_in[10];
  const float* db1 = (const float*)d_in[11];
  const float* dw2 = (const float*)d_in[12];
  const float* db2 = (const float*)d_in[13];
  float* out = (float*)d_out;

  float* ws = (float*)d_ws;
  float* qw     = ws;                 // 524288 floats
  float* kw     = ws + 524288;        // 524288
  float* vw     = ws + 1048576;       // 524288
  float* biasw  = ws + 1572864;       // 2097152
  float* outpre = ws + 3670016;       // 524288  (total 16 MB)

  qkv_kernel<<<dim3(64, 3), 256, 0, stream>>>(src, Wq, Wk, Wv, qw, kw, vw);
  bias_kernel<<<2048, 256, 0, stream>>>(coords, gw1, gb1, gw2, gb2,
                                        dw1, db1, dw2, db2, biasw);
  attn_kernel<<<4096, 256, 0, stream>>>(qw, kw, vw, biasw, outpre);
  proj_kernel<<<64, 256, 0, stream>>>(outpre, Wo, out, 1);
}

// Round 3
// 143.033 us; speedup vs baseline: 4.4566x; 1.8770x over previous
//
#include <hip/hip_runtime.h>
#include <hip/hip_bf16.h>
#include <math.h>

constexpr int B_ = 2;
constexpr int N_ = 1024;
constexpr int D_ = 256;
constexpr int H_ = 8;
constexpr int DH_ = 32;
constexpr float SCALE_ = 0.17677669529663687f;  // 1/sqrt(32)
constexpr float EPSV_ = 1e-4f;

typedef __attribute__((ext_vector_type(8))) short short8;
typedef __attribute__((ext_vector_type(4))) float f32x4;

__device__ __forceinline__ unsigned short f2bf(float x) {
  __hip_bfloat16 h = __float2bfloat16(x);
  return __builtin_bit_cast(unsigned short, h);
}

// ---------------------------------------------------------------------------
// Fast lgamma for x in (0, 2]:  A&S 6.1.36 poly for Gamma(1+y), |err|<=3e-7.
// ---------------------------------------------------------------------------
__device__ __forceinline__ float lgamma_fast(float x) {
  float y = (x < 1.f) ? x : (x - 1.f);
  float g = fmaf(y, 0.035868343f, -0.193527818f);
  g = fmaf(y, g, 0.482199394f);
  g = fmaf(y, g, -0.756704078f);
  g = fmaf(y, g, 0.918206857f);
  g = fmaf(y, g, -0.897056937f);
  g = fmaf(y, g, 0.988205891f);
  g = fmaf(y, g, -0.577191652f);
  g = fmaf(y, g, 1.0f);
  float lg = __logf(g);
  return (x < 1.f) ? lg - __logf(x) : lg;
}

__device__ __forceinline__ float softplus_fast(float x) {
  return __logf(1.f + __expf(x));
}

// ---------------------------------------------------------------------------
// 32-row tile GEMM body: acc[r] = sum_k in[r0+r][k] * W[tid][k]
// ---------------------------------------------------------------------------
__device__ __forceinline__
void gemm32(const float* __restrict__ in, const float* __restrict__ W,
            int r0, float (&acc)[32]) {
  __shared__ float s_lds[32][36];
  __shared__ float w_lds[256][33];
  const int tid = threadIdx.x;
#pragma unroll
  for (int r = 0; r < 32; ++r) acc[r] = 0.f;

  for (int k0 = 0; k0 < D_; k0 += 32) {
    __syncthreads();
#pragma unroll
    for (int it = 0; it < 4; ++it) {
      int idx = tid + it * 256;
      int r = idx >> 5, kk = idx & 31;
      s_lds[kk][r] = in[(r0 + r) * D_ + k0 + kk];
    }
#pragma unroll
    for (int it = 0; it < 32; ++it) {
      int idx = tid + it * 256;
      int o = idx >> 5, kk = idx & 31;
      w_lds[o][kk] = W[o * D_ + k0 + kk];
    }
    __syncthreads();
    float wreg[32];
#pragma unroll
    for (int kk = 0; kk < 32; ++kk) wreg[kk] = w_lds[tid][kk];
#pragma unroll
    for (int kk = 0; kk < 32; ++kk) {
#pragma unroll
      for (int r = 0; r < 32; ++r) acc[r] += s_lds[kk][r] * wreg[kk];
    }
  }
}

// ---------------------------------------------------------------------------
// QKV projections -> bf16. q,k: headed row-major [bh][n][32].
// v: transposed [bh][32][n] so PV MFMA B-frags are contiguous.
// ---------------------------------------------------------------------------
__global__ __launch_bounds__(256)
void qkv_kernel(const float* __restrict__ src,
                const float* __restrict__ Wq, const float* __restrict__ Wk,
                const float* __restrict__ Wv,
                unsigned short* __restrict__ qbf, unsigned short* __restrict__ kbf,
                unsigned short* __restrict__ vtbf) {
  const int y = blockIdx.y;
  const float* W = (y == 0) ? Wq : (y == 1) ? Wk : Wv;
  const int r0 = blockIdx.x * 32;
  float acc[32];
  gemm32(src, W, r0, acc);

  const int o = threadIdx.x, h = o >> 5, d = o & 31;
  if (y < 2) {
    unsigned short* dst = (y == 0) ? qbf : kbf;
#pragma unroll
    for (int r = 0; r < 32; ++r) {
      int rr = r0 + r, b = rr >> 10, n = rr & 1023;
      dst[(size_t)((b * H_ + h) * N_ + n) * DH_ + d] = f2bf(acc[r]);
    }
  } else {
    int b = r0 >> 10, n0 = r0 & 1023;  // block never crosses batch boundary
    unsigned short* dst = vtbf + (size_t)((b * H_ + h) * DH_ + d) * N_ + n0;
#pragma unroll
    for (int r = 0; r < 32; r += 2) {
      ushort2 u2 = make_ushort2(f2bf(acc[r]), f2bf(acc[r + 1]));
      *(ushort2*)&dst[r] = u2;
    }
  }
}

// ---------------------------------------------------------------------------
// Final output projection (f32 in, f32 out, flat layout)
// ---------------------------------------------------------------------------
__global__ __launch_bounds__(256)
void proj_kernel(const float* __restrict__ in, const float* __restrict__ W,
                 float* __restrict__ out) {
  const int r0 = blockIdx.x * 32;
  float acc[32];
  gemm32(in, W, r0, acc);
  const int o = threadIdx.x;
#pragma unroll
  for (int r = 0; r < 32; ++r) out[(r0 + r) * D_ + o] = acc[r];
}

// ---------------------------------------------------------------------------
// Pair-bias kernel (unchanged from round 2: no spills, fast lgamma).
// ---------------------------------------------------------------------------
__global__ __launch_bounds__(256)
void bias_kernel(const float* __restrict__ coords,
                 const float* __restrict__ gw1, const float* __restrict__ gb1,
                 const float* __restrict__ gw2, const float* __restrict__ gb2,
                 const float* __restrict__ dw1, const float* __restrict__ db1,
                 const float* __restrict__ dw2, const float* __restrict__ db2,
                 float* __restrict__ bias) {
  __shared__ float4 swA[64];
  __shared__ float4 swB[64];
  __shared__ float4 swC[64];
  const int tid = threadIdx.x;
  if (tid < 64) {
    int h = tid;
    swA[h] = make_float4(gw1[2 * h], gw1[2 * h + 1], gb1[h], gw2[h]);
    swB[h] = make_float4(dw1[4 * h], dw1[4 * h + 1], dw1[4 * h + 2], dw1[4 * h + 3]);
    swC[h] = make_float4(db1[h], dw2[h], dw2[64 + h], 0.f);
  }
  __syncthreads();

  const int bi = blockIdx.x;
  const int jt = bi & 3;
  const int it = (bi >> 2) & 255;
  const int b  = bi >> 10;
  const int j  = jt * 256 + tid;
  const int ibase = it * 4;

  const float4 cj = ((const float4*)coords)[b * N_ + j];
  float dist[4], dtv[4];
#pragma unroll
  for (int ii = 0; ii < 4; ++ii) {
    float4 ci = ((const float4*)coords)[b * N_ + ibase + ii];
    float dx = ci.x - cj.x, dy = ci.y - cj.y, dz = ci.z - cj.z;
    dist[ii] = sqrtf(dx * dx + dy * dy + dz * dz);
    dtv[ii]  = ci.w - cj.w;
  }

  const float db20 = db2[0], db21 = db2[1], gb20 = gb2[0];
  float biasv[4], raw0[4], raw1[4];
#pragma unroll
  for (int ii = 0; ii < 4; ++ii) { biasv[ii] = 0.f; raw0[ii] = db20; raw1[ii] = db21; }

#pragma unroll 8
  for (int h = 0; h < 64; ++h) {
    float4 a = swA[h], w = swB[h], c = swC[h];
    float dp = fmaf(w.y, cj.x, fmaf(w.z, cj.y, fmaf(w.w, cj.z, c.x)));
#pragma unroll
    for (int ii = 0; ii < 4; ++ii) {
      float g = fmaf(a.x, dist[ii], fmaf(a.y, dtv[ii], a.z));
      biasv[ii] = fmaf(a.w, fmaxf(g, 0.f), biasv[ii]);
      float dh_ = fmaxf(fmaf(w.x, dist[ii], dp), 0.f);
      raw0[ii] = fmaf(c.y, dh_, raw0[ii]);
      raw1[ii] = fmaf(c.z, dh_, raw1[ii]);
    }
  }

#pragma unroll
  for (int ii = 0; ii < 4; ++ii) {
    float sh  = softplus_fast(raw0[ii]) + EPSV_;
    float ra  = softplus_fast(raw1[ii]) + EPSV_;
    float dtp = fmaxf(fabsf(dtv[ii]), EPSV_);
    float lp  = sh * __logf(ra) + (sh - 1.f) * __logf(dtp) - ra * dtp - lgamma_fast(sh);
    bias[(size_t)(b * N_ + ibase + ii) * N_ + j] = biasv[ii] + gb20 + lp;
  }
}

// ---------------------------------------------------------------------------
// MFMA flash attention. 4 independent waves/block (no barriers), wave = 16
// q-rows of one (b,h), full j sweep in 64-wide tiles.
// A-frag: lane holds M-row (l&15), k = (l>>4)*8..+8 (contiguous bf16x8).
// B-frag: lane holds N-col (l&15), k = (l>>4)*8..+8 (contiguous bf16x8).
// C/D:    col = l&15, row = (l>>4)*4 + reg  [verified m89/m91].
// ---------------------------------------------------------------------------
__global__ __launch_bounds__(256)
void attn_kernel(const unsigned short* __restrict__ qbf,
                 const unsigned short* __restrict__ kbf,
                 const unsigned short* __restrict__ vtbf,
                 const float* __restrict__ biasg,
                 float* __restrict__ outpre) {
  __shared__ __align__(16) unsigned short p_lds[4][16][72];  // stride 144B

  const int tid = threadIdx.x;
  const int w = tid >> 6, l = tid & 63;
  const int lr = l & 15, lg = l >> 4;
  const int bh = blockIdx.x >> 4;
  const int qb = blockIdx.x & 15;
  const int b = bh >> 3, h = bh & 7;
  const int ibase = qb * 64 + w * 16;

  const short8 qfrag =
      *(const short8*)(qbf + (size_t)(bh * N_ + ibase + lr) * DH_ + lg * 8);
  const unsigned short* kb = kbf + (size_t)bh * N_ * DH_;
  const unsigned short* vb = vtbf + (size_t)bh * DH_ * N_;
  const float* bbase = biasg + (size_t)b * N_ * N_;

  f32x4 acc[2];
  acc[0] = (f32x4){0.f, 0.f, 0.f, 0.f};
  acc[1] = (f32x4){0.f, 0.f, 0.f, 0.f};
  float m_run[4], l_run[4];
#pragma unroll
  for (int r = 0; r < 4; ++r) { m_run[r] = -3e38f; l_run[r] = 0.f; }

  for (int j0 = 0; j0 < N_; j0 += 64) {
    // ---- QK^T: 4 MFMAs -> S[16 rows][64 cols] (f32, 16 regs) ----
    f32x4 s[4];
#pragma unroll
    for (int t = 0; t < 4; ++t) {
      short8 kf = *(const short8*)(kb + (size_t)(j0 + t * 16 + lr) * DH_ + lg * 8);
      s[t] = __builtin_amdgcn_mfma_f32_16x16x32_bf16(
          qfrag, kf, (f32x4){0.f, 0.f, 0.f, 0.f}, 0, 0, 0);
    }
    // ---- scale + bias ----
#pragma unroll
    for (int r = 0; r < 4; ++r) {
      const float* bi = bbase + (size_t)(ibase + lg * 4 + r) * N_ + j0 + lr;
#pragma unroll
      for (int t = 0; t < 4; ++t)
        s[t][r] = fmaf(s[t][r], SCALE_, bi[t * 16]);
    }
    // ---- online softmax (row = lg*4+r, cols across 16 lanes x 4 tiles) ----
    float mt[4];
#pragma unroll
    for (int r = 0; r < 4; ++r)
      mt[r] = fmaxf(fmaxf(s[0][r], s[1][r]), fmaxf(s[2][r], s[3][r]));
#pragma unroll
    for (int off = 1; off < 16; off <<= 1)
#pragma unroll
      for (int r = 0; r < 4; ++r)
        mt[r] = fmaxf(mt[r], __shfl_xor(mt[r], off));
    float corr[4];
#pragma unroll
    for (int r = 0; r < 4; ++r) {
      float mn = fmaxf(m_run[r], mt[r]);
      corr[r] = __expf(m_run[r] - mn);
      m_run[r] = mn;
    }
#pragma unroll
    for (int t = 0; t < 4; ++t)
#pragma unroll
      for (int r = 0; r < 4; ++r)
        s[t][r] = __expf(s[t][r] - m_run[r]);
    float ps[4];
#pragma unroll
    for (int r = 0; r < 4; ++r)
      ps[r] = (s[0][r] + s[1][r]) + (s[2][r] + s[3][r]);
#pragma unroll
    for (int off = 1; off < 16; off <<= 1)
#pragma unroll
      for (int r = 0; r < 4; ++r)
        ps[r] += __shfl_xor(ps[r], off);
#pragma unroll
    for (int r = 0; r < 4; ++r)
      l_run[r] = l_run[r] * corr[r] + ps[r];
#pragma unroll
    for (int c = 0; c < 2; ++c)
#pragma unroll
      for (int r = 0; r < 4; ++r)
        acc[c][r] *= corr[r];
    // ---- P -> LDS (bf16, row-major, padded stride) ----
#pragma unroll
    for (int t = 0; t < 4; ++t)
#pragma unroll
      for (int r = 0; r < 4; ++r)
        p_lds[w][lg * 4 + r][t * 16 + lr] = f2bf(s[t][r]);
    // ---- PV: A = P (LDS re-fragment), B = Vt (global, contiguous) ----
#pragma unroll
    for (int kc = 0; kc < 2; ++kc) {
      short8 pf = *(const short8*)&p_lds[w][lr][kc * 32 + lg * 8];
#pragma unroll
      for (int c = 0; c < 2; ++c) {
        short8 vf = *(const short8*)(vb + (size_t)(c * 16 + lr) * N_ +
                                     j0 + kc * 32 + lg * 8);
        acc[c] = __builtin_amdgcn_mfma_f32_16x16x32_bf16(pf, vf, acc[c], 0, 0, 0);
      }
    }
  }

  // ---- epilogue: normalize, write [b][n][h*32+d] f32 ----
#pragma unroll
  for (int c = 0; c < 2; ++c) {
    float inv;
#pragma unroll
    for (int r = 0; r < 4; ++r) {
      int i = ibase + lg * 4 + r;
      int d = c * 16 + lr;
      outpre[(size_t)(b * N_ + i) * D_ + h * DH_ + d] = acc[c][r] / l_run[r];
    }
    (void)inv;
  }
}

// ---------------------------------------------------------------------------
extern "C" void kernel_launch(void* const* d_in, const int* in_sizes, int n_in,
                              void* d_out, int out_size, void* d_ws, size_t ws_size,
                              hipStream_t stream) {
  const float* src    = (const float*)d_in[0];
  const float* coords = (const float*)d_in[1];
  const float* Wq  = (const float*)d_in[2];
  const float* Wk  = (const float*)d_in[3];
  const float* Wv  = (const float*)d_in[4];
  const float* Wo  = (const float*)d_in[5];
  const float* gw1 = (const float*)d_in[6];
  const float* gb1 = (const float*)d_in[7];
  const float* gw2 = (const float*)d_in[8];
  const float* gb2 = (const float*)d_in[9];
  const float* dw1 = (const float*)d_in[10];
  const float* db1 = (const float*)d_in[11];
  const float* dw2 = (const float*)d_in[12];
  const float* db2 = (const float*)d_in[13];
  float* out = (float*)d_out;

  char* wsb = (char*)d_ws;
  unsigned short* qbf  = (unsigned short*)wsb;                    // 1 MB
  unsigned short* kbf  = (unsigned short*)(wsb + (1 << 20));      // 1 MB
  unsigned short* vtbf = (unsigned short*)(wsb + (2 << 20));      // 1 MB
  float* biasw  = (float*)(wsb + (3 << 20));                      // 8 MB
  float* outpre = (float*)(wsb + (11 << 20));                     // 2 MB

  qkv_kernel<<<dim3(64, 3), 256, 0, stream>>>(src, Wq, Wk, Wv, qbf, kbf, vtbf);
  bias_kernel<<<2048, 256, 0, stream>>>(coords, gw1, gb1, gw2, gb2,
                                        dw1, db1, dw2, db2, biasw);
  attn_kernel<<<256, 256, 0, stream>>>(qbf, kbf, vtbf, biasw, outpre);
  proj_kernel<<<64, 256, 0, stream>>>(outpre, Wo, out);
}

// Round 4
// 100.266 us; speedup vs baseline: 6.3575x; 1.4265x over previous
//
#include <hip/hip_runtime.h>
#include <hip/hip_bf16.h>
#include <math.h>

constexpr int B_ = 2;
constexpr int N_ = 1024;
constexpr int D_ = 256;
constexpr int H_ = 8;
constexpr int DH_ = 32;
constexpr float SCALE_ = 0.17677669529663687f;  // 1/sqrt(32)
constexpr float EPSV_ = 1e-4f;

typedef __attribute__((ext_vector_type(8))) short short8;
typedef __attribute__((ext_vector_type(4))) float f32x4;

__device__ __forceinline__ unsigned short f2bf(float x) {
  __hip_bfloat16 h = __float2bfloat16(x);
  return __builtin_bit_cast(unsigned short, h);
}
__device__ __forceinline__ float bf2f(unsigned short u) {
  unsigned int x = ((unsigned int)u) << 16;
  return __builtin_bit_cast(float, x);
}

// Split 8 consecutive f32 into bf16 hi + bf16 lo (residual). hi+lo captures
// the f32 value to ~2^-17 relative; lo*lo cross term (~2^-18) is dropped.
__device__ __forceinline__ void split8(const float* __restrict__ p,
                                       short8& hi, short8& lo) {
  f32x4 f0 = *(const f32x4*)p;
  f32x4 f1 = *(const f32x4*)(p + 4);
#pragma unroll
  for (int i = 0; i < 4; ++i) {
    unsigned short h0 = f2bf(f0[i]);
    hi[i] = (short)h0;
    lo[i] = (short)f2bf(f0[i] - bf2f(h0));
    unsigned short h1 = f2bf(f1[i]);
    hi[4 + i] = (short)h1;
    lo[4 + i] = (short)f2bf(f1[i] - bf2f(h1));
  }
}

// ---------------------------------------------------------------------------
// Split-bf16 MFMA GEMM wave body: C[16 rows][64 cols] for one wave.
// acc[ct] C-tile: row = (l>>4)*4 + reg, col = ct*16 + (l&15)  [m89/m91 layout]
// A-frag: lane holds row (l&15), k = (l>>4)*8 .. +8 (verified in attn r3).
// 3 MFMAs per (hi,lo) pair give ~f32 accuracy at MFMA rate.
// ---------------------------------------------------------------------------
__device__ __forceinline__
void mfma_proj_wave(const float* __restrict__ A, const float* __restrict__ W,
                    int r0, int c0, f32x4 (&acc)[4]) {
  const int l = threadIdx.x & 63;
  const int lr = l & 15, lg = l >> 4;
#pragma unroll
  for (int ct = 0; ct < 4; ++ct) acc[ct] = (f32x4){0.f, 0.f, 0.f, 0.f};
#pragma unroll 2
  for (int ks = 0; ks < 8; ++ks) {
    short8 ahi, alo;
    split8(A + (size_t)(r0 + lr) * D_ + ks * 32 + lg * 8, ahi, alo);
#pragma unroll
    for (int ct = 0; ct < 4; ++ct) {
      short8 whi, wlo;
      split8(W + (size_t)(c0 + ct * 16 + lr) * D_ + ks * 32 + lg * 8, whi, wlo);
      acc[ct] = __builtin_amdgcn_mfma_f32_16x16x32_bf16(ahi, whi, acc[ct], 0, 0, 0);
      acc[ct] = __builtin_amdgcn_mfma_f32_16x16x32_bf16(alo, whi, acc[ct], 0, 0, 0);
      acc[ct] = __builtin_amdgcn_mfma_f32_16x16x32_bf16(ahi, wlo, acc[ct], 0, 0, 0);
    }
  }
}

// ---------------------------------------------------------------------------
// QKV projections (MFMA). q,k: bf16 headed [bh][n][32]; v: bf16 [bh][32][n].
// grid (32, 4, 3); block 256 = 4 waves, wave = 16 rows x 64 cols.
// ---------------------------------------------------------------------------
__global__ __launch_bounds__(256)
void qkv_kernel(const float* __restrict__ src,
                const float* __restrict__ Wq, const float* __restrict__ Wk,
                const float* __restrict__ Wv,
                unsigned short* __restrict__ qbf, unsigned short* __restrict__ kbf,
                unsigned short* __restrict__ vtbf) {
  const int z = blockIdx.z;
  const float* W = (z == 0) ? Wq : (z == 1) ? Wk : Wv;
  const int w = threadIdx.x >> 6;
  const int r0 = blockIdx.x * 64 + w * 16;
  const int c0 = blockIdx.y * 64;
  f32x4 acc[4];
  mfma_proj_wave(src, W, r0, c0, acc);

  const int l = threadIdx.x & 63, lr = l & 15, lg = l >> 4;
  if (z < 2) {
    unsigned short* dst = (z == 0) ? qbf : kbf;
#pragma unroll
    for (int ct = 0; ct < 4; ++ct) {
      int o = c0 + ct * 16 + lr, h = o >> 5, d = o & 31;
#pragma unroll
      for (int r = 0; r < 4; ++r) {
        int R = r0 + lg * 4 + r, b = R >> 10, n = R & 1023;
        dst[(size_t)((b * H_ + h) * N_ + n) * DH_ + d] = f2bf(acc[ct][r]);
      }
    }
  } else {
#pragma unroll
    for (int ct = 0; ct < 4; ++ct) {
      int o = c0 + ct * 16 + lr, h = o >> 5, d = o & 31;
#pragma unroll
      for (int r = 0; r < 4; ++r) {
        int R = r0 + lg * 4 + r, b = R >> 10, n = R & 1023;
        vtbf[(size_t)((b * H_ + h) * DH_ + d) * N_ + n] = f2bf(acc[ct][r]);
      }
    }
  }
}

// ---------------------------------------------------------------------------
// Output projection (MFMA, f32 out, flat). grid (32, 4).
// ---------------------------------------------------------------------------
__global__ __launch_bounds__(256)
void projo_kernel(const float* __restrict__ in, const float* __restrict__ W,
                  float* __restrict__ out) {
  const int w = threadIdx.x >> 6;
  const int r0 = blockIdx.x * 64 + w * 16;
  const int c0 = blockIdx.y * 64;
  f32x4 acc[4];
  mfma_proj_wave(in, W, r0, c0, acc);
  const int l = threadIdx.x & 63, lr = l & 15, lg = l >> 4;
#pragma unroll
  for (int ct = 0; ct < 4; ++ct)
#pragma unroll
    for (int r = 0; r < 4; ++r)
      out[(size_t)(r0 + lg * 4 + r) * D_ + c0 + ct * 16 + lr] = acc[ct][r];
}

// ---------------------------------------------------------------------------
// Fast lgamma for x in (0, 2]:  A&S 6.1.36 poly, |err|<=3e-7.
// ---------------------------------------------------------------------------
__device__ __forceinline__ float lgamma_fast(float x) {
  float y = (x < 1.f) ? x : (x - 1.f);
  float g = fmaf(y, 0.035868343f, -0.193527818f);
  g = fmaf(y, g, 0.482199394f);
  g = fmaf(y, g, -0.756704078f);
  g = fmaf(y, g, 0.918206857f);
  g = fmaf(y, g, -0.897056937f);
  g = fmaf(y, g, 0.988205891f);
  g = fmaf(y, g, -0.577191652f);
  g = fmaf(y, g, 1.0f);
  float lg = __logf(g);
  return (x < 1.f) ? lg - __logf(x) : lg;
}

__device__ __forceinline__ float softplus_fast(float x) {
  return __logf(1.f + __expf(x));
}

// ---------------------------------------------------------------------------
// Pair-bias kernel (round-2 version: no spills, fast lgamma).
// ---------------------------------------------------------------------------
__global__ __launch_bounds__(256)
void bias_kernel(const float* __restrict__ coords,
                 const float* __restrict__ gw1, const float* __restrict__ gb1,
                 const float* __restrict__ gw2, const float* __restrict__ gb2,
                 const float* __restrict__ dw1, const float* __restrict__ db1,
                 const float* __restrict__ dw2, const float* __restrict__ db2,
                 float* __restrict__ bias) {
  __shared__ float4 swA[64];
  __shared__ float4 swB[64];
  __shared__ float4 swC[64];
  const int tid = threadIdx.x;
  if (tid < 64) {
    int h = tid;
    swA[h] = make_float4(gw1[2 * h], gw1[2 * h + 1], gb1[h], gw2[h]);
    swB[h] = make_float4(dw1[4 * h], dw1[4 * h + 1], dw1[4 * h + 2], dw1[4 * h + 3]);
    swC[h] = make_float4(db1[h], dw2[h], dw2[64 + h], 0.f);
  }
  __syncthreads();

  const int bi = blockIdx.x;
  const int jt = bi & 3;
  const int it = (bi >> 2) & 255;
  const int b  = bi >> 10;
  const int j  = jt * 256 + tid;
  const int ibase = it * 4;

  const float4 cj = ((const float4*)coords)[b * N_ + j];
  float dist[4], dtv[4];
#pragma unroll
  for (int ii = 0; ii < 4; ++ii) {
    float4 ci = ((const float4*)coords)[b * N_ + ibase + ii];
    float dx = ci.x - cj.x, dy = ci.y - cj.y, dz = ci.z - cj.z;
    dist[ii] = sqrtf(dx * dx + dy * dy + dz * dz);
    dtv[ii]  = ci.w - cj.w;
  }

  const float db20 = db2[0], db21 = db2[1], gb20 = gb2[0];
  float biasv[4], raw0[4], raw1[4];
#pragma unroll
  for (int ii = 0; ii < 4; ++ii) { biasv[ii] = 0.f; raw0[ii] = db20; raw1[ii] = db21; }

#pragma unroll 8
  for (int h = 0; h < 64; ++h) {
    float4 a = swA[h], w = swB[h], c = swC[h];
    float dp = fmaf(w.y, cj.x, fmaf(w.z, cj.y, fmaf(w.w, cj.z, c.x)));
#pragma unroll
    for (int ii = 0; ii < 4; ++ii) {
      float g = fmaf(a.x, dist[ii], fmaf(a.y, dtv[ii], a.z));
      biasv[ii] = fmaf(a.w, fmaxf(g, 0.f), biasv[ii]);
      float dh_ = fmaxf(fmaf(w.x, dist[ii], dp), 0.f);
      raw0[ii] = fmaf(c.y, dh_, raw0[ii]);
      raw1[ii] = fmaf(c.z, dh_, raw1[ii]);
    }
  }

#pragma unroll
  for (int ii = 0; ii < 4; ++ii) {
    float sh  = softplus_fast(raw0[ii]) + EPSV_;
    float ra  = softplus_fast(raw1[ii]) + EPSV_;
    float dtp = fmaxf(fabsf(dtv[ii]), EPSV_);
    float lp  = sh * __logf(ra) + (sh - 1.f) * __logf(dtp) - ra * dtp - lgamma_fast(sh);
    bias[(size_t)(b * N_ + ibase + ii) * N_ + j] = biasv[ii] + gb20 + lp;
  }
}

// ---------------------------------------------------------------------------
// MFMA flash attention (round-3 version, verified).
// ---------------------------------------------------------------------------
__global__ __launch_bounds__(256)
void attn_kernel(const unsigned short* __restrict__ qbf,
                 const unsigned short* __restrict__ kbf,
                 const unsigned short* __restrict__ vtbf,
                 const float* __restrict__ biasg,
                 float* __restrict__ outpre) {
  __shared__ __align__(16) unsigned short p_lds[4][16][72];

  const int tid = threadIdx.x;
  const int w = tid >> 6, l = tid & 63;
  const int lr = l & 15, lg = l >> 4;
  const int bh = blockIdx.x >> 4;
  const int qb = blockIdx.x & 15;
  const int b = bh >> 3, h = bh & 7;
  const int ibase = qb * 64 + w * 16;

  const short8 qfrag =
      *(const short8*)(qbf + (size_t)(bh * N_ + ibase + lr) * DH_ + lg * 8);
  const unsigned short* kb = kbf + (size_t)bh * N_ * DH_;
  const unsigned short* vb = vtbf + (size_t)bh * DH_ * N_;
  const float* bbase = biasg + (size_t)b * N_ * N_;

  f32x4 acc[2];
  acc[0] = (f32x4){0.f, 0.f, 0.f, 0.f};
  acc[1] = (f32x4){0.f, 0.f, 0.f, 0.f};
  float m_run[4], l_run[4];
#pragma unroll
  for (int r = 0; r < 4; ++r) { m_run[r] = -3e38f; l_run[r] = 0.f; }

  for (int j0 = 0; j0 < N_; j0 += 64) {
    f32x4 s[4];
#pragma unroll
    for (int t = 0; t < 4; ++t) {
      short8 kf = *(const short8*)(kb + (size_t)(j0 + t * 16 + lr) * DH_ + lg * 8);
      s[t] = __builtin_amdgcn_mfma_f32_16x16x32_bf16(
          qfrag, kf, (f32x4){0.f, 0.f, 0.f, 0.f}, 0, 0, 0);
    }
#pragma unroll
    for (int r = 0; r < 4; ++r) {
      const float* bi = bbase + (size_t)(ibase + lg * 4 + r) * N_ + j0 + lr;
#pragma unroll
      for (int t = 0; t < 4; ++t)
        s[t][r] = fmaf(s[t][r], SCALE_, bi[t * 16]);
    }
    float mt[4];
#pragma unroll
    for (int r = 0; r < 4; ++r)
      mt[r] = fmaxf(fmaxf(s[0][r], s[1][r]), fmaxf(s[2][r], s[3][r]));
#pragma unroll
    for (int off = 1; off < 16; off <<= 1)
#pragma unroll
      for (int r = 0; r < 4; ++r)
        mt[r] = fmaxf(mt[r], __shfl_xor(mt[r], off));
    float corr[4];
#pragma unroll
    for (int r = 0; r < 4; ++r) {
      float mn = fmaxf(m_run[r], mt[r]);
      corr[r] = __expf(m_run[r] - mn);
      m_run[r] = mn;
    }
#pragma unroll
    for (int t = 0; t < 4; ++t)
#pragma unroll
      for (int r = 0; r < 4; ++r)
        s[t][r] = __expf(s[t][r] - m_run[r]);
    float ps[4];
#pragma unroll
    for (int r = 0; r < 4; ++r)
      ps[r] = (s[0][r] + s[1][r]) + (s[2][r] + s[3][r]);
#pragma unroll
    for (int off = 1; off < 16; off <<= 1)
#pragma unroll
      for (int r = 0; r < 4; ++r)
        ps[r] += __shfl_xor(ps[r], off);
#pragma unroll
    for (int r = 0; r < 4; ++r)
      l_run[r] = l_run[r] * corr[r] + ps[r];
#pragma unroll
    for (int c = 0; c < 2; ++c)
#pragma unroll
      for (int r = 0; r < 4; ++r)
        acc[c][r] *= corr[r];
#pragma unroll
    for (int t = 0; t < 4; ++t)
#pragma unroll
      for (int r = 0; r < 4; ++r)
        p_lds[w][lg * 4 + r][t * 16 + lr] = f2bf(s[t][r]);
#pragma unroll
    for (int kc = 0; kc < 2; ++kc) {
      short8 pf = *(const short8*)&p_lds[w][lr][kc * 32 + lg * 8];
#pragma unroll
      for (int c = 0; c < 2; ++c) {
        short8 vf = *(const short8*)(vb + (size_t)(c * 16 + lr) * N_ +
                                     j0 + kc * 32 + lg * 8);
        acc[c] = __builtin_amdgcn_mfma_f32_16x16x32_bf16(pf, vf, acc[c], 0, 0, 0);
      }
    }
  }

#pragma unroll
  for (int c = 0; c < 2; ++c) {
#pragma unroll
    for (int r = 0; r < 4; ++r) {
      int i = ibase + lg * 4 + r;
      int d = c * 16 + lr;
      outpre[(size_t)(b * N_ + i) * D_ + h * DH_ + d] = acc[c][r] / l_run[r];
    }
  }
}

// ---------------------------------------------------------------------------
extern "C" void kernel_launch(void* const* d_in, const int* in_sizes, int n_in,
                              void* d_out, int out_size, void* d_ws, size_t ws_size,
                              hipStream_t stream) {
  const float* src    = (const float*)d_in[0];
  const float* coords = (const float*)d_in[1];
  const float* Wq  = (const float*)d_in[2];
  const float* Wk  = (const float*)d_in[3];
  const float* Wv  = (const float*)d_in[4];
  const float* Wo  = (const float*)d_in[5];
  const float* gw1 = (const float*)d_in[6];
  const float* gb1 = (const float*)d_in[7];
  const float* gw2 = (const float*)d_in[8];
  const float* gb2 = (const float*)d_in[9];
  const float* dw1 = (const float*)d_in[10];
  const float* db1 = (const float*)d_in[11];
  const float* dw2 = (const float*)d_in[12];
  const float* db2 = (const float*)d_in[13];
  float* out = (float*)d_out;

  char* wsb = (char*)d_ws;
  unsigned short* qbf  = (unsigned short*)wsb;                    // 1 MB
  unsigned short* kbf  = (unsigned short*)(wsb + (1 << 20));      // 1 MB
  unsigned short* vtbf = (unsigned short*)(wsb + (2 << 20));      // 1 MB
  float* biasw  = (float*)(wsb + (3 << 20));                      // 8 MB
  float* outpre = (float*)(wsb + (11 << 20));                     // 2 MB

  qkv_kernel<<<dim3(32, 4, 3), 256, 0, stream>>>(src, Wq, Wk, Wv, qbf, kbf, vtbf);
  bias_kernel<<<2048, 256, 0, stream>>>(coords, gw1, gb1, gw2, gb2,
                                        dw1, db1, dw2, db2, biasw);
  attn_kernel<<<256, 256, 0, stream>>>(qbf, kbf, vtbf, biasw, outpre);
  projo_kernel<<<dim3(32, 4), 256, 0, stream>>>(outpre, Wo, out);
}

// Round 5
// 96.794 us; speedup vs baseline: 6.5856x; 1.0359x over previous
//
#include <hip/hip_runtime.h>
#include <hip/hip_bf16.h>
#include <math.h>

constexpr int B_ = 2;
constexpr int N_ = 1024;
constexpr int D_ = 256;
constexpr int H_ = 8;
constexpr int DH_ = 32;
constexpr float SCALE_ = 0.17677669529663687f;  // 1/sqrt(32)
constexpr float EPSV_ = 1e-4f;

typedef __attribute__((ext_vector_type(8))) short short8;
typedef __attribute__((ext_vector_type(4))) float f32x4;

__device__ __forceinline__ unsigned short f2bf(float x) {
  __hip_bfloat16 h = __float2bfloat16(x);
  return __builtin_bit_cast(unsigned short, h);
}
__device__ __forceinline__ float bf2f(unsigned short u) {
  unsigned int x = ((unsigned int)u) << 16;
  return __builtin_bit_cast(float, x);
}

// Split 8 consecutive f32 into bf16 hi + bf16 lo (residual).
__device__ __forceinline__ void split8(const float* __restrict__ p,
                                       short8& hi, short8& lo) {
  f32x4 f0 = *(const f32x4*)p;
  f32x4 f1 = *(const f32x4*)(p + 4);
#pragma unroll
  for (int i = 0; i < 4; ++i) {
    unsigned short h0 = f2bf(f0[i]);
    hi[i] = (short)h0;
    lo[i] = (short)f2bf(f0[i] - bf2f(h0));
    unsigned short h1 = f2bf(f1[i]);
    hi[4 + i] = (short)h1;
    lo[4 + i] = (short)f2bf(f1[i] - bf2f(h1));
  }
}

// ---------------------------------------------------------------------------
// One-shot weight split: Wq,Wk,Wv,Wo (4 x 256 x 256 f32) -> bf16 hi/lo tables.
// Removes the per-wave redundant W split8 in the GEMM kernels.
// ---------------------------------------------------------------------------
__global__ __launch_bounds__(256)
void wsplit_kernel(const float* __restrict__ Wq, const float* __restrict__ Wk,
                   const float* __restrict__ Wv, const float* __restrict__ Wo,
                   unsigned short* __restrict__ whi, unsigned short* __restrict__ wlo) {
  int t = blockIdx.x * 256 + threadIdx.x;   // 0..65535
  int idx4 = t * 4;
  int m = idx4 >> 16;
  int off = idx4 & 65535;
  const float* W = (m == 0) ? Wq : (m == 1) ? Wk : (m == 2) ? Wv : Wo;
  float4 f = *(const float4*)(W + off);
  ushort4 hi, lo;
  hi.x = f2bf(f.x); lo.x = f2bf(f.x - bf2f(hi.x));
  hi.y = f2bf(f.y); lo.y = f2bf(f.y - bf2f(hi.y));
  hi.z = f2bf(f.z); lo.z = f2bf(f.z - bf2f(hi.z));
  hi.w = f2bf(f.w); lo.w = f2bf(f.w - bf2f(hi.w));
  *(ushort4*)(whi + idx4) = hi;
  *(ushort4*)(wlo + idx4) = lo;
}

// ---------------------------------------------------------------------------
// Split-bf16 MFMA GEMM wave body, pre-split W. C[16 rows][64 cols] per wave.
// acc row = (l>>4)*4 + reg, col = ct*16 + (l&15)  [m89/m91 layout].
// ---------------------------------------------------------------------------
__device__ __forceinline__
void mfma_proj_wave(const float* __restrict__ A,
                    const unsigned short* __restrict__ whi,
                    const unsigned short* __restrict__ wlo,
                    int r0, int c0, f32x4 (&acc)[4]) {
  const int l = threadIdx.x & 63;
  const int lr = l & 15, lg = l >> 4;
#pragma unroll
  for (int ct = 0; ct < 4; ++ct) acc[ct] = (f32x4){0.f, 0.f, 0.f, 0.f};
#pragma unroll 2
  for (int ks = 0; ks < 8; ++ks) {
    short8 ahi, alo;
    split8(A + (size_t)(r0 + lr) * D_ + ks * 32 + lg * 8, ahi, alo);
#pragma unroll
    for (int ct = 0; ct < 4; ++ct) {
      size_t woff = (size_t)(c0 + ct * 16 + lr) * D_ + ks * 32 + lg * 8;
      short8 wh = *(const short8*)(whi + woff);
      short8 wl = *(const short8*)(wlo + woff);
      acc[ct] = __builtin_amdgcn_mfma_f32_16x16x32_bf16(ahi, wh, acc[ct], 0, 0, 0);
      acc[ct] = __builtin_amdgcn_mfma_f32_16x16x32_bf16(alo, wh, acc[ct], 0, 0, 0);
      acc[ct] = __builtin_amdgcn_mfma_f32_16x16x32_bf16(ahi, wl, acc[ct], 0, 0, 0);
    }
  }
}

// ---------------------------------------------------------------------------
// QKV projections (MFMA, pre-split W). grid (32, 4, 3); 4 waves/block.
// ---------------------------------------------------------------------------
__global__ __launch_bounds__(256)
void qkv_kernel(const float* __restrict__ src,
                const unsigned short* __restrict__ whi,
                const unsigned short* __restrict__ wlo,
                unsigned short* __restrict__ qbf, unsigned short* __restrict__ kbf,
                unsigned short* __restrict__ vtbf) {
  const int z = blockIdx.z;
  const int w = threadIdx.x >> 6;
  const int r0 = blockIdx.x * 64 + w * 16;
  const int c0 = blockIdx.y * 64;
  f32x4 acc[4];
  mfma_proj_wave(src, whi + z * 65536, wlo + z * 65536, r0, c0, acc);

  const int l = threadIdx.x & 63, lr = l & 15, lg = l >> 4;
  if (z < 2) {
    unsigned short* dst = (z == 0) ? qbf : kbf;
#pragma unroll
    for (int ct = 0; ct < 4; ++ct) {
      int o = c0 + ct * 16 + lr, h = o >> 5, d = o & 31;
#pragma unroll
      for (int r = 0; r < 4; ++r) {
        int R = r0 + lg * 4 + r, b = R >> 10, n = R & 1023;
        dst[(size_t)((b * H_ + h) * N_ + n) * DH_ + d] = f2bf(acc[ct][r]);
      }
    }
  } else {
#pragma unroll
    for (int ct = 0; ct < 4; ++ct) {
      int o = c0 + ct * 16 + lr, h = o >> 5, d = o & 31;
#pragma unroll
      for (int r = 0; r < 4; ++r) {
        int R = r0 + lg * 4 + r, b = R >> 10, n = R & 1023;
        vtbf[(size_t)((b * H_ + h) * DH_ + d) * N_ + n] = f2bf(acc[ct][r]);
      }
    }
  }
}

// ---------------------------------------------------------------------------
// Output projection (MFMA, pre-split Wo at table offset 3). grid (32, 4).
// ---------------------------------------------------------------------------
__global__ __launch_bounds__(256)
void projo_kernel(const float* __restrict__ in,
                  const unsigned short* __restrict__ whi,
                  const unsigned short* __restrict__ wlo,
                  float* __restrict__ out) {
  const int w = threadIdx.x >> 6;
  const int r0 = blockIdx.x * 64 + w * 16;
  const int c0 = blockIdx.y * 64;
  f32x4 acc[4];
  mfma_proj_wave(in, whi + 3 * 65536, wlo + 3 * 65536, r0, c0, acc);
  const int l = threadIdx.x & 63, lr = l & 15, lg = l >> 4;
#pragma unroll
  for (int ct = 0; ct < 4; ++ct)
#pragma unroll
    for (int r = 0; r < 4; ++r)
      out[(size_t)(r0 + lg * 4 + r) * D_ + c0 + ct * 16 + lr] = acc[ct][r];
}

// ---------------------------------------------------------------------------
// Fast lgamma for x in (0, 2]:  A&S 6.1.36 poly, |err|<=3e-7.
// ---------------------------------------------------------------------------
__device__ __forceinline__ float lgamma_fast(float x) {
  float y = (x < 1.f) ? x : (x - 1.f);
  float g = fmaf(y, 0.035868343f, -0.193527818f);
  g = fmaf(y, g, 0.482199394f);
  g = fmaf(y, g, -0.756704078f);
  g = fmaf(y, g, 0.918206857f);
  g = fmaf(y, g, -0.897056937f);
  g = fmaf(y, g, 0.988205891f);
  g = fmaf(y, g, -0.577191652f);
  g = fmaf(y, g, 1.0f);
  float lg = __logf(g);
  return (x < 1.f) ? lg - __logf(x) : lg;
}

__device__ __forceinline__ float softplus_fast(float x) {
  return __logf(1.f + __expf(x));
}

// ---------------------------------------------------------------------------
// Pair-bias kernel (unchanged; ~VALU floor at full occupancy).
// ---------------------------------------------------------------------------
__global__ __launch_bounds__(256)
void bias_kernel(const float* __restrict__ coords,
                 const float* __restrict__ gw1, const float* __restrict__ gb1,
                 const float* __restrict__ gw2, const float* __restrict__ gb2,
                 const float* __restrict__ dw1, const float* __restrict__ db1,
                 const float* __restrict__ dw2, const float* __restrict__ db2,
                 float* __restrict__ bias) {
  __shared__ float4 swA[64];
  __shared__ float4 swB[64];
  __shared__ float4 swC[64];
  const int tid = threadIdx.x;
  if (tid < 64) {
    int h = tid;
    swA[h] = make_float4(gw1[2 * h], gw1[2 * h + 1], gb1[h], gw2[h]);
    swB[h] = make_float4(dw1[4 * h], dw1[4 * h + 1], dw1[4 * h + 2], dw1[4 * h + 3]);
    swC[h] = make_float4(db1[h], dw2[h], dw2[64 + h], 0.f);
  }
  __syncthreads();

  const int bi = blockIdx.x;
  const int jt = bi & 3;
  const int it = (bi >> 2) & 255;
  const int b  = bi >> 10;
  const int j  = jt * 256 + tid;
  const int ibase = it * 4;

  const float4 cj = ((const float4*)coords)[b * N_ + j];
  float dist[4], dtv[4];
#pragma unroll
  for (int ii = 0; ii < 4; ++ii) {
    float4 ci = ((const float4*)coords)[b * N_ + ibase + ii];
    float dx = ci.x - cj.x, dy = ci.y - cj.y, dz = ci.z - cj.z;
    dist[ii] = sqrtf(dx * dx + dy * dy + dz * dz);
    dtv[ii]  = ci.w - cj.w;
  }

  const float db20 = db2[0], db21 = db2[1], gb20 = gb2[0];
  float biasv[4], raw0[4], raw1[4];
#pragma unroll
  for (int ii = 0; ii < 4; ++ii) { biasv[ii] = 0.f; raw0[ii] = db20; raw1[ii] = db21; }

#pragma unroll 8
  for (int h = 0; h < 64; ++h) {
    float4 a = swA[h], w = swB[h], c = swC[h];
    float dp = fmaf(w.y, cj.x, fmaf(w.z, cj.y, fmaf(w.w, cj.z, c.x)));
#pragma unroll
    for (int ii = 0; ii < 4; ++ii) {
      float g = fmaf(a.x, dist[ii], fmaf(a.y, dtv[ii], a.z));
      biasv[ii] = fmaf(a.w, fmaxf(g, 0.f), biasv[ii]);
      float dh_ = fmaxf(fmaf(w.x, dist[ii], dp), 0.f);
      raw0[ii] = fmaf(c.y, dh_, raw0[ii]);
      raw1[ii] = fmaf(c.z, dh_, raw1[ii]);
    }
  }

#pragma unroll
  for (int ii = 0; ii < 4; ++ii) {
    float sh  = softplus_fast(raw0[ii]) + EPSV_;
    float ra  = softplus_fast(raw1[ii]) + EPSV_;
    float dtp = fmaxf(fabsf(dtv[ii]), EPSV_);
    float lp  = sh * __logf(ra) + (sh - 1.f) * __logf(dtp) - ra * dtp - lgamma_fast(sh);
    bias[(size_t)(b * N_ + ibase + ii) * N_ + j] = biasv[ii] + gb20 + lp;
  }
}

// ---------------------------------------------------------------------------
// MFMA flash attention, split-j. Block = 512 threads = 8 waves:
// wave w -> row-subtile s = w>>1 (16 rows), j-half jh = w&1 (512 j's).
// 2048 waves total = 2 waves/SIMD (was 1). Halves merged flash-style via LDS.
// ---------------------------------------------------------------------------
__global__ __launch_bounds__(512)
void attn_kernel(const unsigned short* __restrict__ qbf,
                 const unsigned short* __restrict__ kbf,
                 const unsigned short* __restrict__ vtbf,
                 const float* __restrict__ biasg,
                 float* __restrict__ outpre) {
  __shared__ __align__(16) unsigned short p_lds[8][16][72];  // per-wave P tile
  __shared__ float acc_lds[4][16][32];   // jh==1 partial acc
  __shared__ float ml_lds[4][16][2];     // jh==1 partial m,l

  const int tid = threadIdx.x;
  const int w = tid >> 6, l = tid & 63;
  const int s = w >> 1, jh = w & 1;
  const int lr = l & 15, lg = l >> 4;
  const int bh = blockIdx.x >> 4;
  const int qb = blockIdx.x & 15;
  const int b = bh >> 3, h = bh & 7;
  const int ibase = qb * 64 + s * 16;

  const short8 qfrag =
      *(const short8*)(qbf + (size_t)(bh * N_ + ibase + lr) * DH_ + lg * 8);
  const unsigned short* kb = kbf + (size_t)bh * N_ * DH_;
  const unsigned short* vb = vtbf + (size_t)bh * DH_ * N_;
  const float* bbase = biasg + (size_t)b * N_ * N_;

  f32x4 acc[2];
  acc[0] = (f32x4){0.f, 0.f, 0.f, 0.f};
  acc[1] = (f32x4){0.f, 0.f, 0.f, 0.f};
  float m_run[4], l_run[4];
#pragma unroll
  for (int r = 0; r < 4; ++r) { m_run[r] = -3e38f; l_run[r] = 0.f; }

  const int jbeg = jh * 512;
  for (int j0 = jbeg; j0 < jbeg + 512; j0 += 64) {
    f32x4 sc[4];
#pragma unroll
    for (int t = 0; t < 4; ++t) {
      short8 kf = *(const short8*)(kb + (size_t)(j0 + t * 16 + lr) * DH_ + lg * 8);
      sc[t] = __builtin_amdgcn_mfma_f32_16x16x32_bf16(
          qfrag, kf, (f32x4){0.f, 0.f, 0.f, 0.f}, 0, 0, 0);
    }
#pragma unroll
    for (int r = 0; r < 4; ++r) {
      const float* bi = bbase + (size_t)(ibase + lg * 4 + r) * N_ + j0 + lr;
#pragma unroll
      for (int t = 0; t < 4; ++t)
        sc[t][r] = fmaf(sc[t][r], SCALE_, bi[t * 16]);
    }
    float mt[4];
#pragma unroll
    for (int r = 0; r < 4; ++r)
      mt[r] = fmaxf(fmaxf(sc[0][r], sc[1][r]), fmaxf(sc[2][r], sc[3][r]));
#pragma unroll
    for (int off = 1; off < 16; off <<= 1)
#pragma unroll
      for (int r = 0; r < 4; ++r)
        mt[r] = fmaxf(mt[r], __shfl_xor(mt[r], off));
    float corr[4];
#pragma unroll
    for (int r = 0; r < 4; ++r) {
      float mn = fmaxf(m_run[r], mt[r]);
      corr[r] = __expf(m_run[r] - mn);
      m_run[r] = mn;
    }
#pragma unroll
    for (int t = 0; t < 4; ++t)
#pragma unroll
      for (int r = 0; r < 4; ++r)
        sc[t][r] = __expf(sc[t][r] - m_run[r]);
    float ps[4];
#pragma unroll
    for (int r = 0; r < 4; ++r)
      ps[r] = (sc[0][r] + sc[1][r]) + (sc[2][r] + sc[3][r]);
#pragma unroll
    for (int off = 1; off < 16; off <<= 1)
#pragma unroll
      for (int r = 0; r < 4; ++r)
        ps[r] += __shfl_xor(ps[r], off);
#pragma unroll
    for (int r = 0; r < 4; ++r)
      l_run[r] = l_run[r] * corr[r] + ps[r];
#pragma unroll
    for (int c = 0; c < 2; ++c)
#pragma unroll
      for (int r = 0; r < 4; ++r)
        acc[c][r] *= corr[r];
#pragma unroll
    for (int t = 0; t < 4; ++t)
#pragma unroll
      for (int r = 0; r < 4; ++r)
        p_lds[w][lg * 4 + r][t * 16 + lr] = f2bf(sc[t][r]);
#pragma unroll
    for (int kc = 0; kc < 2; ++kc) {
      short8 pf = *(const short8*)&p_lds[w][lr][kc * 32 + lg * 8];
#pragma unroll
      for (int c = 0; c < 2; ++c) {
        short8 vf = *(const short8*)(vb + (size_t)(c * 16 + lr) * N_ +
                                     j0 + kc * 32 + lg * 8);
        acc[c] = __builtin_amdgcn_mfma_f32_16x16x32_bf16(pf, vf, acc[c], 0, 0, 0);
      }
    }
  }

  // ---- merge j-halves: jh==1 publishes partials, jh==0 combines+writes ----
  if (jh == 1) {
#pragma unroll
    for (int c = 0; c < 2; ++c)
#pragma unroll
      for (int r = 0; r < 4; ++r)
        acc_lds[s][lg * 4 + r][c * 16 + lr] = acc[c][r];
    if (lr == 0) {
#pragma unroll
      for (int r = 0; r < 4; ++r) {
        ml_lds[s][lg * 4 + r][0] = m_run[r];
        ml_lds[s][lg * 4 + r][1] = l_run[r];
      }
    }
  }
  __syncthreads();
  if (jh == 0) {
    float c0[4], c1[4], linv[4];
#pragma unroll
    for (int r = 0; r < 4; ++r) {
      int row = lg * 4 + r;
      float m1 = ml_lds[s][row][0], l1 = ml_lds[s][row][1];
      float m = fmaxf(m_run[r], m1);
      c0[r] = __expf(m_run[r] - m);
      c1[r] = __expf(m1 - m);
      linv[r] = 1.f / (l_run[r] * c0[r] + l1 * c1[r]);
    }
#pragma unroll
    for (int c = 0; c < 2; ++c) {
#pragma unroll
      for (int r = 0; r < 4; ++r) {
        int row = lg * 4 + r;
        int i = ibase + row;
        int d = c * 16 + lr;
        float o = (acc[c][r] * c0[r] + acc_lds[s][row][d] * c1[r]) * linv[r];
        outpre[(size_t)(b * N_ + i) * D_ + h * DH_ + d] = o;
      }
    }
  }
}

// ---------------------------------------------------------------------------
extern "C" void kernel_launch(void* const* d_in, const int* in_sizes, int n_in,
                              void* d_out, int out_size, void* d_ws, size_t ws_size,
                              hipStream_t stream) {
  const float* src    = (const float*)d_in[0];
  const float* coords = (const float*)d_in[1];
  const float* Wq  = (const float*)d_in[2];
  const float* Wk  = (const float*)d_in[3];
  const float* Wv  = (const float*)d_in[4];
  const float* Wo  = (const float*)d_in[5];
  const float* gw1 = (const float*)d_in[6];
  const float* gb1 = (const float*)d_in[7];
  const float* gw2 = (const float*)d_in[8];
  const float* gb2 = (const float*)d_in[9];
  const float* dw1 = (const float*)d_in[10];
  const float* db1 = (const float*)d_in[11];
  const float* dw2 = (const float*)d_in[12];
  const float* db2 = (const float*)d_in[13];
  float* out = (float*)d_out;

  char* wsb = (char*)d_ws;
  unsigned short* qbf  = (unsigned short*)wsb;                    // 1 MB
  unsigned short* kbf  = (unsigned short*)(wsb + (1 << 20));      // 1 MB
  unsigned short* vtbf = (unsigned short*)(wsb + (2 << 20));      // 1 MB
  float* biasw  = (float*)(wsb + (3 << 20));                      // 8 MB
  float* outpre = (float*)(wsb + (11 << 20));                     // 2 MB
  unsigned short* whi = (unsigned short*)(wsb + (13 << 20));      // 512 KB
  unsigned short* wlo = (unsigned short*)(wsb + (13 << 20) + (512 << 10));

  wsplit_kernel<<<256, 256, 0, stream>>>(Wq, Wk, Wv, Wo, whi, wlo);
  qkv_kernel<<<dim3(32, 4, 3), 256, 0, stream>>>(src, whi, wlo, qbf, kbf, vtbf);
  bias_kernel<<<2048, 256, 0, stream>>>(coords, gw1, gb1, gw2, gb2,
                                        dw1, db1, dw2, db2, biasw);
  attn_kernel<<<256, 512, 0, stream>>>(qbf, kbf, vtbf, biasw, outpre);
  projo_kernel<<<dim3(32, 4), 256, 0, stream>>>(outpre, whi, wlo, out);
}

// Round 6
// 94.537 us; speedup vs baseline: 6.7428x; 1.0239x over previous
//
#include <hip/hip_runtime.h>
#include <hip/hip_bf16.h>
#include <math.h>

constexpr int B_ = 2;
constexpr int N_ = 1024;
constexpr int D_ = 256;
constexpr int H_ = 8;
constexpr int DH_ = 32;
constexpr float SCALE_ = 0.17677669529663687f;  // 1/sqrt(32)
constexpr float EPSV_ = 1e-4f;

typedef __attribute__((ext_vector_type(8))) short short8;
typedef __attribute__((ext_vector_type(4))) float f32x4;

__device__ __forceinline__ unsigned short f2bf(float x) {
  __hip_bfloat16 h = __float2bfloat16(x);
  return __builtin_bit_cast(unsigned short, h);
}
__device__ __forceinline__ float bf2f(unsigned short u) {
  unsigned int x = ((unsigned int)u) << 16;
  return __builtin_bit_cast(float, x);
}

// ---------------------------------------------------------------------------
// One-shot split of Wq,Wk,Wv,Wo (4 x 64K f32) AND src (512K f32) into bf16
// hi/lo tables. After this, all GEMM kernels are pure load + MFMA.
// grid 768 x 256, 4 floats/thread.
// ---------------------------------------------------------------------------
__global__ __launch_bounds__(256)
void split_kernel(const float* __restrict__ Wq, const float* __restrict__ Wk,
                  const float* __restrict__ Wv, const float* __restrict__ Wo,
                  const float* __restrict__ src,
                  unsigned short* __restrict__ whi, unsigned short* __restrict__ wlo,
                  unsigned short* __restrict__ shi, unsigned short* __restrict__ slo) {
  int t = blockIdx.x * 256 + threadIdx.x;   // 0..196607
  int idx4 = t * 4;
  const float* p;
  unsigned short *dhi, *dlo;
  int off;
  if (idx4 < 262144) {                      // W region
    int m = idx4 >> 16;
    off = idx4 & 65535;
    p = (m == 0) ? Wq : (m == 1) ? Wk : (m == 2) ? Wv : Wo;
    dhi = whi + idx4; dlo = wlo + idx4;
  } else {                                  // src region
    off = idx4 - 262144;
    p = src;
    dhi = shi + off; dlo = slo + off;
  }
  float4 f = *(const float4*)(p + off);
  ushort4 hi, lo;
  hi.x = f2bf(f.x); lo.x = f2bf(f.x - bf2f(hi.x));
  hi.y = f2bf(f.y); lo.y = f2bf(f.y - bf2f(hi.y));
  hi.z = f2bf(f.z); lo.z = f2bf(f.z - bf2f(hi.z));
  hi.w = f2bf(f.w); lo.w = f2bf(f.w - bf2f(hi.w));
  *(ushort4*)dhi = hi;
  *(ushort4*)dlo = lo;
}

// ---------------------------------------------------------------------------
// Pure-load split-bf16 MFMA GEMM wave body. C[16 rows][64 cols] per wave.
// acc row = (l>>4)*4 + reg, col = ct*16 + (l&15)  [m89/m91 layout].
// a*w ~= ahi*whi + alo*whi + ahi*wlo (drops lo*lo ~ 2^-18 rel).
// ---------------------------------------------------------------------------
__device__ __forceinline__
void mfma_wave_pure(const unsigned short* __restrict__ Ahi,
                    const unsigned short* __restrict__ Alo,
                    const unsigned short* __restrict__ whi,
                    const unsigned short* __restrict__ wlo,
                    int r0, int c0, f32x4 (&acc)[4]) {
  const int l = threadIdx.x & 63;
  const int lr = l & 15, lg = l >> 4;
#pragma unroll
  for (int ct = 0; ct < 4; ++ct) acc[ct] = (f32x4){0.f, 0.f, 0.f, 0.f};
#pragma unroll 2
  for (int ks = 0; ks < 8; ++ks) {
    size_t aoff = (size_t)(r0 + lr) * D_ + ks * 32 + lg * 8;
    short8 ahi = *(const short8*)(Ahi + aoff);
    short8 alo = *(const short8*)(Alo + aoff);
#pragma unroll
    for (int ct = 0; ct < 4; ++ct) {
      size_t woff = (size_t)(c0 + ct * 16 + lr) * D_ + ks * 32 + lg * 8;
      short8 wh = *(const short8*)(whi + woff);
      short8 wl = *(const short8*)(wlo + woff);
      acc[ct] = __builtin_amdgcn_mfma_f32_16x16x32_bf16(ahi, wh, acc[ct], 0, 0, 0);
      acc[ct] = __builtin_amdgcn_mfma_f32_16x16x32_bf16(alo, wh, acc[ct], 0, 0, 0);
      acc[ct] = __builtin_amdgcn_mfma_f32_16x16x32_bf16(ahi, wl, acc[ct], 0, 0, 0);
    }
  }
}

// ---------------------------------------------------------------------------
// QKV projections. grid (32, 4, 3); 4 waves/block.
// ---------------------------------------------------------------------------
__global__ __launch_bounds__(256)
void qkv_kernel(const unsigned short* __restrict__ shi,
                const unsigned short* __restrict__ slo,
                const unsigned short* __restrict__ whi,
                const unsigned short* __restrict__ wlo,
                unsigned short* __restrict__ qbf, unsigned short* __restrict__ kbf,
                unsigned short* __restrict__ vtbf) {
  const int z = blockIdx.z;
  const int w = threadIdx.x >> 6;
  const int r0 = blockIdx.x * 64 + w * 16;
  const int c0 = blockIdx.y * 64;
  f32x4 acc[4];
  mfma_wave_pure(shi, slo, whi + z * 65536, wlo + z * 65536, r0, c0, acc);

  const int l = threadIdx.x & 63, lr = l & 15, lg = l >> 4;
  if (z < 2) {
    unsigned short* dst = (z == 0) ? qbf : kbf;
#pragma unroll
    for (int ct = 0; ct < 4; ++ct) {
      int o = c0 + ct * 16 + lr, h = o >> 5, d = o & 31;
#pragma unroll
      for (int r = 0; r < 4; ++r) {
        int R = r0 + lg * 4 + r, b = R >> 10, n = R & 1023;
        dst[(size_t)((b * H_ + h) * N_ + n) * DH_ + d] = f2bf(acc[ct][r]);
      }
    }
  } else {
#pragma unroll
    for (int ct = 0; ct < 4; ++ct) {
      int o = c0 + ct * 16 + lr, h = o >> 5, d = o & 31;
#pragma unroll
      for (int r = 0; r < 4; ++r) {
        int R = r0 + lg * 4 + r, b = R >> 10, n = R & 1023;
        vtbf[(size_t)((b * H_ + h) * DH_ + d) * N_ + n] = f2bf(acc[ct][r]);
      }
    }
  }
}

// ---------------------------------------------------------------------------
// Output projection: A = attn output pre-split (hi/lo bf16), f32 out.
// ---------------------------------------------------------------------------
__global__ __launch_bounds__(256)
void projo_kernel(const unsigned short* __restrict__ ophi,
                  const unsigned short* __restrict__ oplo,
                  const unsigned short* __restrict__ whi,
                  const unsigned short* __restrict__ wlo,
                  float* __restrict__ out) {
  const int w = threadIdx.x >> 6;
  const int r0 = blockIdx.x * 64 + w * 16;
  const int c0 = blockIdx.y * 64;
  f32x4 acc[4];
  mfma_wave_pure(ophi, oplo, whi + 3 * 65536, wlo + 3 * 65536, r0, c0, acc);
  const int l = threadIdx.x & 63, lr = l & 15, lg = l >> 4;
#pragma unroll
  for (int ct = 0; ct < 4; ++ct)
#pragma unroll
    for (int r = 0; r < 4; ++r)
      out[(size_t)(r0 + lg * 4 + r) * D_ + c0 + ct * 16 + lr] = acc[ct][r];
}

// ---------------------------------------------------------------------------
// Fast lgamma for x in (0, 2]:  A&S 6.1.36 poly, |err|<=3e-7.
// ---------------------------------------------------------------------------
__device__ __forceinline__ float lgamma_fast(float x) {
  float y = (x < 1.f) ? x : (x - 1.f);
  float g = fmaf(y, 0.035868343f, -0.193527818f);
  g = fmaf(y, g, 0.482199394f);
  g = fmaf(y, g, -0.756704078f);
  g = fmaf(y, g, 0.918206857f);
  g = fmaf(y, g, -0.897056937f);
  g = fmaf(y, g, 0.988205891f);
  g = fmaf(y, g, -0.577191652f);
  g = fmaf(y, g, 1.0f);
  float lg = __logf(g);
  return (x < 1.f) ? lg - __logf(x) : lg;
}

__device__ __forceinline__ float softplus_fast(float x) {
  return __logf(1.f + __expf(x));
}

// ---------------------------------------------------------------------------
// Pair-bias kernel v3: one j per thread, SIXTEEN i's per thread.
// LDS weight-broadcast reads per pair drop 4x vs v2 (was the LDS-issue
// bottleneck: 192 ds_read_b128/thread at 4 pairs); VALU ~8 ops/pair-h is the
// floor. 512 blocks x 256 threads.
// ---------------------------------------------------------------------------
__global__ __launch_bounds__(256)
void bias_kernel(const float* __restrict__ coords,
                 const float* __restrict__ gw1, const float* __restrict__ gb1,
                 const float* __restrict__ gw2, const float* __restrict__ gb2,
                 const float* __restrict__ dw1, const float* __restrict__ db1,
                 const float* __restrict__ dw2, const float* __restrict__ db2,
                 float* __restrict__ bias) {
  __shared__ float4 swA[64];   // g0, g1, gb1, g2
  __shared__ float4 swB[64];   // d_dist, d_x, d_y, d_z
  __shared__ float4 swC[64];   // db1, w0, w1, pad
  __shared__ float4 ci_lds[16];
  const int tid = threadIdx.x;

  const int bi = blockIdx.x;
  const int jt = bi & 3;            // 4 j-tiles of 256
  const int it = (bi >> 2) & 63;    // 64 i-tiles of 16
  const int b  = bi >> 8;
  const int j  = jt * 256 + tid;
  const int ibase = it * 16;

  if (tid < 64) {
    int h = tid;
    swA[h] = make_float4(gw1[2 * h], gw1[2 * h + 1], gb1[h], gw2[h]);
    swB[h] = make_float4(dw1[4 * h], dw1[4 * h + 1], dw1[4 * h + 2], dw1[4 * h + 3]);
    swC[h] = make_float4(db1[h], dw2[h], dw2[64 + h], 0.f);
  } else if (tid < 80) {
    ci_lds[tid - 64] = ((const float4*)coords)[b * N_ + ibase + (tid - 64)];
  }
  __syncthreads();

  const float4 cj = ((const float4*)coords)[b * N_ + j];
  float dist[16], dtv[16];
#pragma unroll
  for (int ii = 0; ii < 16; ++ii) {
    float4 ci = ci_lds[ii];
    float dx = ci.x - cj.x, dy = ci.y - cj.y, dz = ci.z - cj.z;
    dist[ii] = sqrtf(dx * dx + dy * dy + dz * dz);
    dtv[ii]  = ci.w - cj.w;
  }

  const float db20 = db2[0], db21 = db2[1], gb20 = gb2[0];
  float biasv[16], raw0[16], raw1[16];
#pragma unroll
  for (int ii = 0; ii < 16; ++ii) { biasv[ii] = 0.f; raw0[ii] = db20; raw1[ii] = db21; }

#pragma unroll 2
  for (int h = 0; h < 64; ++h) {
    float4 a = swA[h], w = swB[h], c = swC[h];
    float dp = fmaf(w.y, cj.x, fmaf(w.z, cj.y, fmaf(w.w, cj.z, c.x)));
#pragma unroll
    for (int ii = 0; ii < 16; ++ii) {
      float g = fmaf(a.x, dist[ii], fmaf(a.y, dtv[ii], a.z));
      biasv[ii] = fmaf(a.w, fmaxf(g, 0.f), biasv[ii]);
      float dh_ = fmaxf(fmaf(w.x, dist[ii], dp), 0.f);
      raw0[ii] = fmaf(c.y, dh_, raw0[ii]);
      raw1[ii] = fmaf(c.z, dh_, raw1[ii]);
    }
  }

#pragma unroll 4
  for (int ii = 0; ii < 16; ++ii) {
    float sh  = softplus_fast(raw0[ii]) + EPSV_;
    float ra  = softplus_fast(raw1[ii]) + EPSV_;
    float dtp = fmaxf(fabsf(dtv[ii]), EPSV_);
    float lp  = sh * __logf(ra) + (sh - 1.f) * __logf(dtp) - ra * dtp - lgamma_fast(sh);
    bias[(size_t)(b * N_ + ibase + ii) * N_ + j] = biasv[ii] + gb20 + lp;
  }
}

// ---------------------------------------------------------------------------
// MFMA flash attention, split-j (round-5 structure). Epilogue now emits the
// pre-projection output as bf16 hi/lo so projo is pure load + MFMA.
// ---------------------------------------------------------------------------
__global__ __launch_bounds__(512)
void attn_kernel(const unsigned short* __restrict__ qbf,
                 const unsigned short* __restrict__ kbf,
                 const unsigned short* __restrict__ vtbf,
                 const float* __restrict__ biasg,
                 unsigned short* __restrict__ ophi,
                 unsigned short* __restrict__ oplo) {
  __shared__ __align__(16) unsigned short p_lds[8][16][72];
  __shared__ float acc_lds[4][16][32];
  __shared__ float ml_lds[4][16][2];

  const int tid = threadIdx.x;
  const int w = tid >> 6, l = tid & 63;
  const int s = w >> 1, jh = w & 1;
  const int lr = l & 15, lg = l >> 4;
  const int bh = blockIdx.x >> 4;
  const int qb = blockIdx.x & 15;
  const int b = bh >> 3, h = bh & 7;
  const int ibase = qb * 64 + s * 16;

  const short8 qfrag =
      *(const short8*)(qbf + (size_t)(bh * N_ + ibase + lr) * DH_ + lg * 8);
  const unsigned short* kb = kbf + (size_t)bh * N_ * DH_;
  const unsigned short* vb = vtbf + (size_t)bh * DH_ * N_;
  const float* bbase = biasg + (size_t)b * N_ * N_;

  f32x4 acc[2];
  acc[0] = (f32x4){0.f, 0.f, 0.f, 0.f};
  acc[1] = (f32x4){0.f, 0.f, 0.f, 0.f};
  float m_run[4], l_run[4];
#pragma unroll
  for (int r = 0; r < 4; ++r) { m_run[r] = -3e38f; l_run[r] = 0.f; }

  const int jbeg = jh * 512;
  for (int j0 = jbeg; j0 < jbeg + 512; j0 += 64) {
    f32x4 sc[4];
#pragma unroll
    for (int t = 0; t < 4; ++t) {
      short8 kf = *(const short8*)(kb + (size_t)(j0 + t * 16 + lr) * DH_ + lg * 8);
      sc[t] = __builtin_amdgcn_mfma_f32_16x16x32_bf16(
          qfrag, kf, (f32x4){0.f, 0.f, 0.f, 0.f}, 0, 0, 0);
    }
#pragma unroll
    for (int r = 0; r < 4; ++r) {
      const float* bi = bbase + (size_t)(ibase + lg * 4 + r) * N_ + j0 + lr;
#pragma unroll
      for (int t = 0; t < 4; ++t)
        sc[t][r] = fmaf(sc[t][r], SCALE_, bi[t * 16]);
    }
    float mt[4];
#pragma unroll
    for (int r = 0; r < 4; ++r)
      mt[r] = fmaxf(fmaxf(sc[0][r], sc[1][r]), fmaxf(sc[2][r], sc[3][r]));
#pragma unroll
    for (int off = 1; off < 16; off <<= 1)
#pragma unroll
      for (int r = 0; r < 4; ++r)
        mt[r] = fmaxf(mt[r], __shfl_xor(mt[r], off));
    float corr[4];
#pragma unroll
    for (int r = 0; r < 4; ++r) {
      float mn = fmaxf(m_run[r], mt[r]);
      corr[r] = __expf(m_run[r] - mn);
      m_run[r] = mn;
    }
#pragma unroll
    for (int t = 0; t < 4; ++t)
#pragma unroll
      for (int r = 0; r < 4; ++r)
        sc[t][r] = __expf(sc[t][r] - m_run[r]);
    float ps[4];
#pragma unroll
    for (int r = 0; r < 4; ++r)
      ps[r] = (sc[0][r] + sc[1][r]) + (sc[2][r] + sc[3][r]);
#pragma unroll
    for (int off = 1; off < 16; off <<= 1)
#pragma unroll
      for (int r = 0; r < 4; ++r)
        ps[r] += __shfl_xor(ps[r], off);
#pragma unroll
    for (int r = 0; r < 4; ++r)
      l_run[r] = l_run[r] * corr[r] + ps[r];
#pragma unroll
    for (int c = 0; c < 2; ++c)
#pragma unroll
      for (int r = 0; r < 4; ++r)
        acc[c][r] *= corr[r];
#pragma unroll
    for (int t = 0; t < 4; ++t)
#pragma unroll
      for (int r = 0; r < 4; ++r)
        p_lds[w][lg * 4 + r][t * 16 + lr] = f2bf(sc[t][r]);
#pragma unroll
    for (int kc = 0; kc < 2; ++kc) {
      short8 pf = *(const short8*)&p_lds[w][lr][kc * 32 + lg * 8];
#pragma unroll
      for (int c = 0; c < 2; ++c) {
        short8 vf = *(const short8*)(vb + (size_t)(c * 16 + lr) * N_ +
                                     j0 + kc * 32 + lg * 8);
        acc[c] = __builtin_amdgcn_mfma_f32_16x16x32_bf16(pf, vf, acc[c], 0, 0, 0);
      }
    }
  }

  if (jh == 1) {
#pragma unroll
    for (int c = 0; c < 2; ++c)
#pragma unroll
      for (int r = 0; r < 4; ++r)
        acc_lds[s][lg * 4 + r][c * 16 + lr] = acc[c][r];
    if (lr == 0) {
#pragma unroll
      for (int r = 0; r < 4; ++r) {
        ml_lds[s][lg * 4 + r][0] = m_run[r];
        ml_lds[s][lg * 4 + r][1] = l_run[r];
      }
    }
  }
  __syncthreads();
  if (jh == 0) {
    float c0[4], c1[4], linv[4];
#pragma unroll
    for (int r = 0; r < 4; ++r) {
      int row = lg * 4 + r;
      float m1 = ml_lds[s][row][0], l1 = ml_lds[s][row][1];
      float m = fmaxf(m_run[r], m1);
      c0[r] = __expf(m_run[r] - m);
      c1[r] = __expf(m1 - m);
      linv[r] = 1.f / (l_run[r] * c0[r] + l1 * c1[r]);
    }
#pragma unroll
    for (int c = 0; c < 2; ++c) {
#pragma unroll
      for (int r = 0; r < 4; ++r) {
        int row = lg * 4 + r;
        int i = ibase + row;
        int d = c * 16 + lr;
        float o = (acc[c][r] * c0[r] + acc_lds[s][row][d] * c1[r]) * linv[r];
        size_t oidx = (size_t)(b * N_ + i) * D_ + h * DH_ + d;
        unsigned short hi = f2bf(o);
        ophi[oidx] = hi;
        oplo[oidx] = f2bf(o - bf2f(hi));
      }
    }
  }
}

// ---------------------------------------------------------------------------
extern "C" void kernel_launch(void* const* d_in, const int* in_sizes, int n_in,
                              void* d_out, int out_size, void* d_ws, size_t ws_size,
                              hipStream_t stream) {
  const float* src    = (const float*)d_in[0];
  const float* coords = (const float*)d_in[1];
  const float* Wq  = (const float*)d_in[2];
  const float* Wk  = (const float*)d_in[3];
  const float* Wv  = (const float*)d_in[4];
  const float* Wo  = (const float*)d_in[5];
  const float* gw1 = (const float*)d_in[6];
  const float* gb1 = (const float*)d_in[7];
  const float* gw2 = (const float*)d_in[8];
  const float* gb2 = (const float*)d_in[9];
  const float* dw1 = (const float*)d_in[10];
  const float* db1 = (const float*)d_in[11];
  const float* dw2 = (const float*)d_in[12];
  const float* db2 = (const float*)d_in[13];
  float* out = (float*)d_out;

  char* wsb = (char*)d_ws;
  unsigned short* qbf  = (unsigned short*)wsb;                        // 1 MB
  unsigned short* kbf  = (unsigned short*)(wsb + (1 << 20));          // 1 MB
  unsigned short* vtbf = (unsigned short*)(wsb + (2 << 20));          // 1 MB
  float* biasw         = (float*)(wsb + (3 << 20));                   // 8 MB
  unsigned short* whi  = (unsigned short*)(wsb + (11 << 20));         // 512 KB
  unsigned short* wlo  = (unsigned short*)(wsb + (11 << 20) + (512 << 10));
  unsigned short* shi  = (unsigned short*)(wsb + (12 << 20));         // 1 MB
  unsigned short* slo  = (unsigned short*)(wsb + (13 << 20));         // 1 MB
  unsigned short* ophi = (unsigned short*)(wsb + (14 << 20));         // 1 MB
  unsigned short* oplo = (unsigned short*)(wsb + (15 << 20));         // 1 MB

  split_kernel<<<768, 256, 0, stream>>>(Wq, Wk, Wv, Wo, src, whi, wlo, shi, slo);
  qkv_kernel<<<dim3(32, 4, 3), 256, 0, stream>>>(shi, slo, whi, wlo, qbf, kbf, vtbf);
  bias_kernel<<<512, 256, 0, stream>>>(coords, gw1, gb1, gw2, gb2,
                                       dw1, db1, dw2, db2, biasw);
  attn_kernel<<<256, 512, 0, stream>>>(qbf, kbf, vtbf, biasw, ophi, oplo);
  projo_kernel<<<dim3(32, 4), 256, 0, stream>>>(ophi, oplo, whi, wlo, out);
}